// Round 1
// baseline (16786.218 us; speedup 1.0000x reference)
//
#include <hip/hip_runtime.h>
#include <math.h>

// ---------------- sizes ----------------
// inputs: 0 f2(2,256,200,200) 1 f3(2,256,100,100) 2 f4(2,256,50,50) 3 f5(2,256,25,25)
// 4 boxes(256,4) 5 batch_idx(256) 6 W1(1024,12544) 7 b1 8 W2(1024,1024) 9 b2
// 10 Wc(2,1024) 11 bc 12 Wb(8,1024) 13 bb 14 wd(256,256,2,2) 15 bd 16 wm5(2,256,1,1) 17 bm5
// 18 wm1 19 bm1 20 wm2 21 bm2 22 wm3 23 bm3 24 wm4 25 bm4
// out: cls(256,2) | bbox(256,8) | mask(256,2,28,28)  => 403968 f32

#define N_ROI 256
#define C_F 256

// ws offsets (bytes) -- all multiples of 256
#define OFF_FTR2 0ull
#define OFF_FTR3 81920000ull
#define OFF_FTR4 102400000ull
#define OFF_FTR5 107520000ull
#define OFF_P7   108800000ull   // [n][c][49] f32: 12,845,056 B
#define OFF_H1   121645056ull   // 1MB
#define OFF_H2   122693632ull   // 1MB
#define OFF_PB   123742208ull   // 4MB split-K partials
#define OFF_WDT  127936512ull   // 1MB wdT[tap][i][o]
#define OFF_MA   128985088ull   // 51,380,224 B  [n][196][256]
#define OFF_MB   0ull           // aliases ftr2 region (dead after roi-align)

// ---------------- feat transpose (B,C,H,W)->(B,H,W,C) ----------------
__global__ __launch_bounds__(256) void transpose_feat(const float* __restrict__ src,
                                                      float* __restrict__ dst,
                                                      int C, int H, int W) {
  __shared__ float tile[32][33];
  int w0 = blockIdx.x * 32, c0 = blockIdx.y * 32;
  int b = blockIdx.z / H, h = blockIdx.z % H;
  int tx = threadIdx.x & 31, ty = threadIdx.x >> 5;
#pragma unroll
  for (int i = 0; i < 32; i += 8) {
    int c = c0 + ty + i, w = w0 + tx;
    float v = 0.f;
    if (c < C && w < W) v = src[((size_t)(b * C + c) * H + h) * W + w];
    tile[ty + i][tx] = v;
  }
  __syncthreads();
#pragma unroll
  for (int i = 0; i < 32; i += 8) {
    int w = w0 + ty + i, c = c0 + tx;
    if (c < C && w < W) dst[((size_t)(b * H + h) * W + w) * C + c] = tile[tx][ty + i];
  }
}

// ---------------- wd (o,i,2,2) -> wdT[tap][i][o] ----------------
__global__ __launch_bounds__(256) void transpose_wd(const float* __restrict__ wd,
                                                    float* __restrict__ wdT) {
  int idx = blockIdx.x * 256 + threadIdx.x;   // 262144 total
  int o = idx & 255;
  int rest = idx >> 8;
  int i = rest & 255;
  int tap = rest >> 8;
  wdT[idx] = wd[((size_t)o * 256 + i) * 4 + tap];
}

// ---------------- ROI align (channels-last feats) ----------------
__global__ __launch_bounds__(256) void roi_align_k(
    const float* __restrict__ t2, const float* __restrict__ t3,
    const float* __restrict__ t4, const float* __restrict__ t5,
    const float* __restrict__ boxes, const int* __restrict__ bidx,
    float* __restrict__ outp, int OUT, int CLAST) {
  int n = blockIdx.x, pix = blockIdx.y;
  int oy = pix / OUT, ox = pix % OUT;
  int c = threadIdx.x;
  float bx1 = boxes[n * 4 + 0], by1 = boxes[n * 4 + 1];
  float bx2 = boxes[n * 4 + 2], by2 = boxes[n * 4 + 3];
  float area = (bx2 - bx1) * (by2 - by1);
  float kf = floorf(4.0f + log2f(sqrtf(area) / 224.0f + 1e-6f));
  kf = fminf(fmaxf(kf, 2.0f), 5.0f);
  int lvl = (int)kf - 2;
  float scale = 0.25f / (float)(1 << lvl);
  const float* f = (lvl == 0) ? t2 : (lvl == 1) ? t3 : (lvl == 2) ? t4 : t5;
  int H = 200 >> lvl, W = 200 >> lvl;
  int b = bidx[n];
  float x1 = bx1 * scale, y1 = by1 * scale, x2 = bx2 * scale, y2 = by2 * scale;
  float rw = fmaxf(x2 - x1, 1.0f), rh = fmaxf(y2 - y1, 1.0f);
  int P = OUT * 2;
  float acc = 0.f;
#pragma unroll
  for (int sy = 0; sy < 2; ++sy) {
    float offy = ((float)(oy * 2 + sy) + 0.5f) / (float)P;
    float gy = fminf(fmaxf(y1 + offy * rh, 0.f), (float)(H - 1));
    int yy0 = (int)floorf(gy);
    int yy1 = min(yy0 + 1, H - 1);
    float ly = gy - (float)yy0;
#pragma unroll
    for (int sx = 0; sx < 2; ++sx) {
      float offx = ((float)(ox * 2 + sx) + 0.5f) / (float)P;
      float gx = fminf(fmaxf(x1 + offx * rw, 0.f), (float)(W - 1));
      int xx0 = (int)floorf(gx);
      int xx1 = min(xx0 + 1, W - 1);
      float lx = gx - (float)xx0;
      size_t base = (size_t)b * H * W * 256;
      float v00 = f[base + ((size_t)yy0 * W + xx0) * 256 + c];
      float v01 = f[base + ((size_t)yy0 * W + xx1) * 256 + c];
      float v10 = f[base + ((size_t)yy1 * W + xx0) * 256 + c];
      float v11 = f[base + ((size_t)yy1 * W + xx1) * 256 + c];
      acc += v00 * (1 - ly) * (1 - lx) + v01 * (1 - ly) * lx +
             v10 * ly * (1 - lx) + v11 * ly * lx;
    }
  }
  acc *= 0.25f;
  if (CLAST)
    outp[((size_t)n * OUT * OUT + pix) * 256 + c] = acc;
  else
    outp[((size_t)n * 256 + c) * (OUT * OUT) + pix] = acc;
}

// ---------------- GEMM: C[s] partial = A(M,K) * B(N,K)^T over K-slice s ----------------
__global__ __launch_bounds__(256) void gemm_nt(const float* __restrict__ A,
                                               const float* __restrict__ B,
                                               float* __restrict__ C,
                                               int M, int N, int K) {
  __shared__ float As[32][33];
  __shared__ float Bs[32][33];
  int KS = gridDim.z;
  int kslice = K / KS;
  int k0 = blockIdx.z * kslice;
  int ib = blockIdx.x, jb = blockIdx.y;
  int tid = threadIdx.x;
  int tx = tid & 31, ty = tid >> 5;
  int ti = tid >> 4, tj = tid & 15;
  float a00 = 0, a01 = 0, a10 = 0, a11 = 0;
  const float* Ab = A + (size_t)(ib * 32) * K;
  const float* Bb = B + (size_t)(jb * 32) * K;
  for (int kc = 0; kc < kslice; kc += 32) {
    __syncthreads();
#pragma unroll
    for (int r = 0; r < 4; ++r) {
      As[ty + 8 * r][tx] = Ab[(size_t)(ty + 8 * r) * K + k0 + kc + tx];
      Bs[ty + 8 * r][tx] = Bb[(size_t)(ty + 8 * r) * K + k0 + kc + tx];
    }
    __syncthreads();
#pragma unroll
    for (int k = 0; k < 32; ++k) {
      float av0 = As[2 * ti][k], av1 = As[2 * ti + 1][k];
      float bv0 = Bs[2 * tj][k], bv1 = Bs[2 * tj + 1][k];
      a00 += av0 * bv0; a01 += av0 * bv1; a10 += av1 * bv0; a11 += av1 * bv1;
    }
  }
  size_t co = ((size_t)blockIdx.z * M + ib * 32) * N + jb * 32;
  C[co + (size_t)(2 * ti) * N + 2 * tj] = a00;
  C[co + (size_t)(2 * ti) * N + 2 * tj + 1] = a01;
  C[co + (size_t)(2 * ti + 1) * N + 2 * tj] = a10;
  C[co + (size_t)(2 * ti + 1) * N + 2 * tj + 1] = a11;
}

__global__ __launch_bounds__(256) void reduce_bias_relu(const float* __restrict__ pb,
                                                        const float* __restrict__ bias,
                                                        float* __restrict__ out,
                                                        int MN, int N, int S) {
  int idx = blockIdx.x * 256 + threadIdx.x;
  if (idx >= MN) return;
  float v = 0.f;
  for (int s = 0; s < S; ++s) v += pb[(size_t)s * MN + idx];
  v += bias[idx % N];
  out[idx] = fmaxf(v, 0.f);
}

// ---------------- cls/bbox head ----------------
__global__ __launch_bounds__(256) void head_kernel(const float* __restrict__ h2,
                                                   const float* __restrict__ Wc,
                                                   const float* __restrict__ bc,
                                                   const float* __restrict__ Wb,
                                                   const float* __restrict__ bb,
                                                   float* __restrict__ out) {
  int n = blockIdx.x;
  int tid = threadIdx.x;
  __shared__ float s[1024];
  __shared__ float red[10][4];
#pragma unroll
  for (int r = 0; r < 4; ++r) s[tid + 256 * r] = h2[(size_t)n * 1024 + tid + 256 * r];
  __syncthreads();
  for (int j = 0; j < 10; ++j) {
    const float* w = (j < 2) ? &Wc[j * 1024] : &Wb[(j - 2) * 1024];
    float v = 0.f;
#pragma unroll
    for (int r = 0; r < 4; ++r) v += s[tid + 256 * r] * w[tid + 256 * r];
#pragma unroll
    for (int off = 32; off > 0; off >>= 1) v += __shfl_down(v, off);
    if ((tid & 63) == 0) red[j][tid >> 6] = v;
  }
  __syncthreads();
  if (tid < 10) {
    float v = red[tid][0] + red[tid][1] + red[tid][2] + red[tid][3];
    if (tid < 2) out[n * 2 + tid] = v + bc[tid];
    else out[512 + n * 8 + (tid - 2)] = v + bb[tid - 2];
  }
}

// ---------------- conv3x3 + bias + relu, channels-last 14x14x256 ----------------
__global__ __launch_bounds__(256) void conv3x3_relu(const float* __restrict__ in,
                                                    const float* __restrict__ w,
                                                    const float* __restrict__ bias,
                                                    float* __restrict__ out) {
  int n = blockIdx.x, ot = blockIdx.y;  // o tile of 64
  __shared__ float s_in[196][68];
  int tid = threadIdx.x;
  int o4 = tid & 15, pg = tid >> 4;
  int o = ot * 64 + o4 * 4;
  float acc[13][4];
#pragma unroll
  for (int p = 0; p < 13; ++p)
#pragma unroll
    for (int q = 0; q < 4; ++q) acc[p][q] = 0.f;
  int yv[13], xv[13];
#pragma unroll
  for (int p = 0; p < 13; ++p) {
    int px = p * 16 + pg;
    yv[p] = px / 14;
    xv[p] = px - yv[p] * 14;
  }
  for (int ic = 0; ic < 256; ic += 64) {
    __syncthreads();
#pragma unroll
    for (int r = 0; r < 13; ++r) {
      int slot = r * 256 + tid;
      if (slot < 3136) {
        int px = slot >> 4, c4 = slot & 15;
        float4 v = *reinterpret_cast<const float4*>(
            in + ((size_t)n * 196 + px) * 256 + ic + c4 * 4);
        *reinterpret_cast<float4*>(&s_in[px][c4 * 4]) = v;
      }
    }
    __syncthreads();
    for (int tap = 0; tap < 9; ++tap) {
      int dy = tap / 3 - 1, dx = tap % 3 - 1;
      int dpx = dy * 14 + dx;
      for (int i4 = 0; i4 < 16; ++i4) {
        float wv[4][4];
#pragma unroll
        for (int oo = 0; oo < 4; ++oo)
#pragma unroll
          for (int ii = 0; ii < 4; ++ii)
            wv[oo][ii] = w[((size_t)(o + oo) * 256 + ic + i4 * 4 + ii) * 9 + tap];
#pragma unroll
        for (int p = 0; p < 13; ++p) {
          int yy = yv[p] + dy, xx = xv[p] + dx;
          if (yv[p] < 14 && (unsigned)yy < 14u && (unsigned)xx < 14u) {
            int px = p * 16 + pg;
            const float4 iv =
                *reinterpret_cast<const float4*>(&s_in[px + dpx][i4 * 4]);
#pragma unroll
            for (int oo = 0; oo < 4; ++oo)
              acc[p][oo] += iv.x * wv[oo][0] + iv.y * wv[oo][1] +
                            iv.z * wv[oo][2] + iv.w * wv[oo][3];
          }
        }
      }
    }
  }
#pragma unroll
  for (int p = 0; p < 13; ++p) {
    int px = p * 16 + pg;
    if (px < 196) {
      float4 r;
      r.x = fmaxf(acc[p][0] + bias[o + 0], 0.f);
      r.y = fmaxf(acc[p][1] + bias[o + 1], 0.f);
      r.z = fmaxf(acc[p][2] + bias[o + 2], 0.f);
      r.w = fmaxf(acc[p][3] + bias[o + 3], 0.f);
      *reinterpret_cast<float4*>(out + ((size_t)n * 196 + px) * 256 + o) = r;
    }
  }
}

// ---------------- deconv 2x2 s2 + bias + relu + 1x1 conv to 2ch (fused) ----------------
__global__ __launch_bounds__(256) void deconv_mask(const float* __restrict__ in,   // [n][196][256]
                                                   const float* __restrict__ wdT,  // [tap][i][o]
                                                   const float* __restrict__ bd,
                                                   const float* __restrict__ wm5,  // [2][256]
                                                   const float* __restrict__ bm5,
                                                   float* __restrict__ outp) {
  int n = blockIdx.x, iy = blockIdx.y;
  int o = threadIdx.x;
  __shared__ float s_in[14 * 256];
  __shared__ float s_red[112][4];
#pragma unroll
  for (int r = 0; r < 4; ++r) {
    int slot = r * 256 + threadIdx.x;  // 896 float4 slots
    if (slot < 896)
      *reinterpret_cast<float4*>(&s_in[slot * 4]) =
          *reinterpret_cast<const float4*>(
              in + ((size_t)n * 196 + iy * 14) * 256 + slot * 4);
  }
  __syncthreads();
  float acc[4][14];
#pragma unroll
  for (int t = 0; t < 4; ++t)
#pragma unroll
    for (int ix = 0; ix < 14; ++ix) acc[t][ix] = 0.f;
#pragma unroll 4
  for (int i = 0; i < 256; ++i) {
    float si[14];
#pragma unroll
    for (int ix = 0; ix < 14; ++ix) si[ix] = s_in[ix * 256 + i];
#pragma unroll
    for (int tap = 0; tap < 4; ++tap) {
      float wv = wdT[((size_t)tap * 256 + i) * 256 + o];
#pragma unroll
      for (int ix = 0; ix < 14; ++ix) acc[tap][ix] += si[ix] * wv;
    }
  }
  float bdv = bd[o];
  float w50 = wm5[o], w51 = wm5[256 + o];
  int lane = threadIdx.x & 63, wid = threadIdx.x >> 6;
#pragma unroll
  for (int tap = 0; tap < 4; ++tap) {
#pragma unroll
    for (int ix = 0; ix < 14; ++ix) {
      float rr = fmaxf(acc[tap][ix] + bdv, 0.f);
      float p0 = rr * w50, p1 = rr * w51;
#pragma unroll
      for (int off = 1; off < 64; off <<= 1) {
        p0 += __shfl_xor(p0, off);
        p1 += __shfl_xor(p1, off);
      }
      if (lane == 0) {
        s_red[(tap * 14 + ix) * 2 + 0][wid] = p0;
        s_red[(tap * 14 + ix) * 2 + 1][wid] = p1;
      }
    }
  }
  __syncthreads();
  if (threadIdx.x < 112) {
    int pair = threadIdx.x >> 1, k = threadIdx.x & 1;
    float v = s_red[pair * 2 + k][0] + s_red[pair * 2 + k][1] +
              s_red[pair * 2 + k][2] + s_red[pair * 2 + k][3] + bm5[k];
    int tap = pair / 14, ix = pair % 14;
    int ky = tap >> 1, kx = tap & 1;
    int y = 2 * iy + 1 - ky, x = 2 * ix + 1 - kx;
    outp[2560 + (size_t)n * 1568 + k * 784 + y * 28 + x] = v;
  }
}

// ---------------- launch ----------------
extern "C" void kernel_launch(void* const* d_in, const int* in_sizes, int n_in,
                              void* d_out, int out_size, void* d_ws, size_t ws_size,
                              hipStream_t stream) {
  const float* f2 = (const float*)d_in[0];
  const float* f3 = (const float*)d_in[1];
  const float* f4 = (const float*)d_in[2];
  const float* f5 = (const float*)d_in[3];
  const float* boxes = (const float*)d_in[4];
  const int* bidx = (const int*)d_in[5];
  const float* W1 = (const float*)d_in[6];
  const float* b1 = (const float*)d_in[7];
  const float* W2 = (const float*)d_in[8];
  const float* b2 = (const float*)d_in[9];
  const float* Wc = (const float*)d_in[10];
  const float* bc = (const float*)d_in[11];
  const float* Wb = (const float*)d_in[12];
  const float* bb = (const float*)d_in[13];
  const float* wd = (const float*)d_in[14];
  const float* bd = (const float*)d_in[15];
  const float* wm5 = (const float*)d_in[16];
  const float* bm5 = (const float*)d_in[17];
  const float* wm[4] = {(const float*)d_in[18], (const float*)d_in[20],
                        (const float*)d_in[22], (const float*)d_in[24]};
  const float* bm[4] = {(const float*)d_in[19], (const float*)d_in[21],
                        (const float*)d_in[23], (const float*)d_in[25]};
  char* ws = (char*)d_ws;
  float* ftr2 = (float*)(ws + OFF_FTR2);
  float* ftr3 = (float*)(ws + OFF_FTR3);
  float* ftr4 = (float*)(ws + OFF_FTR4);
  float* ftr5 = (float*)(ws + OFF_FTR5);
  float* p7 = (float*)(ws + OFF_P7);
  float* h1 = (float*)(ws + OFF_H1);
  float* h2 = (float*)(ws + OFF_H2);
  float* pbuf = (float*)(ws + OFF_PB);
  float* wdT = (float*)(ws + OFF_WDT);
  float* mA = (float*)(ws + OFF_MA);
  float* mB = (float*)(ws + OFF_MB);
  float* out = (float*)d_out;

  // feats -> channels-last
  transpose_feat<<<dim3(7, 8, 400), 256, 0, stream>>>(f2, ftr2, 256, 200, 200);
  transpose_feat<<<dim3(4, 8, 200), 256, 0, stream>>>(f3, ftr3, 256, 100, 100);
  transpose_feat<<<dim3(2, 8, 100), 256, 0, stream>>>(f4, ftr4, 256, 50, 50);
  transpose_feat<<<dim3(1, 8, 50), 256, 0, stream>>>(f5, ftr5, 256, 25, 25);
  transpose_wd<<<1024, 256, 0, stream>>>(wd, wdT);

  // ROI align
  roi_align_k<<<dim3(256, 49), 256, 0, stream>>>(ftr2, ftr3, ftr4, ftr5, boxes,
                                                 bidx, p7, 7, 0);
  roi_align_k<<<dim3(256, 196), 256, 0, stream>>>(ftr2, ftr3, ftr4, ftr5, boxes,
                                                  bidx, mA, 14, 1);

  // FC head
  gemm_nt<<<dim3(8, 32, 4), 256, 0, stream>>>(p7, W1, pbuf, 256, 1024, 12544);
  reduce_bias_relu<<<1024, 256, 0, stream>>>(pbuf, b1, h1, 262144, 1024, 4);
  gemm_nt<<<dim3(8, 32, 1), 256, 0, stream>>>(h1, W2, pbuf, 256, 1024, 1024);
  reduce_bias_relu<<<1024, 256, 0, stream>>>(pbuf, b2, h2, 262144, 1024, 1);
  head_kernel<<<256, 256, 0, stream>>>(h2, Wc, bc, Wb, bb, out);

  // mask head
  conv3x3_relu<<<dim3(256, 4), 256, 0, stream>>>(mA, wm[0], bm[0], mB);
  conv3x3_relu<<<dim3(256, 4), 256, 0, stream>>>(mB, wm[1], bm[1], mA);
  conv3x3_relu<<<dim3(256, 4), 256, 0, stream>>>(mA, wm[2], bm[2], mB);
  conv3x3_relu<<<dim3(256, 4), 256, 0, stream>>>(mB, wm[3], bm[3], mA);
  deconv_mask<<<dim3(256, 14), 256, 0, stream>>>(mA, wdT, bd, wm5, bm5, out);
}

// Round 2
// 1133.677 us; speedup vs baseline: 14.8069x; 14.8069x over previous
//
#include <hip/hip_runtime.h>
#include <math.h>

// ---------------- sizes ----------------
// inputs: 0 f2(2,256,200,200) 1 f3(2,256,100,100) 2 f4(2,256,50,50) 3 f5(2,256,25,25)
// 4 boxes(256,4) 5 batch_idx(256) 6 W1(1024,12544) 7 b1 8 W2(1024,1024) 9 b2
// 10 Wc(2,1024) 11 bc 12 Wb(8,1024) 13 bb 14 wd(256,256,2,2) 15 bd 16 wm5(2,256,1,1) 17 bm5
// 18 wm1 19 bm1 20 wm2 21 bm2 22 wm3 23 bm3 24 wm4 25 bm4
// out: cls(256,2) | bbox(256,8) | mask(256,2,28,28)

typedef __attribute__((ext_vector_type(8))) short short8;
typedef __attribute__((ext_vector_type(4))) float f32x4;
typedef unsigned short ushort_t;
typedef unsigned int uint_t;

// ws offsets (bytes)
#define OFF_FTR2 0ull
#define OFF_FTR3 81920000ull
#define OFF_FTR4 102400000ull
#define OFF_FTR5 107520000ull
#define OFF_P7   108800000ull
#define OFF_H1   121645056ull
#define OFF_H2   122693632ull
#define OFF_PB   123742208ull
#define OFF_WDT  127936512ull
#define OFF_MA   128985088ull   // bf16 [n][196][256]: 25,690,112 B
#define OFF_WT   155199488ull   // bf16 [4][9][256][256]: 4,718,592 B
#define OFF_MB   0ull           // aliases ftr2 (dead after roi-align)

__device__ inline ushort_t f2bf(float f) {
  union { float f; uint_t u; } v; v.f = f;
  uint_t r = (v.u + 0x7fffu + ((v.u >> 16) & 1u)) >> 16;
  return (ushort_t)r;
}
__device__ inline float bf2f(ushort_t b) {
  union { uint_t u; float f; } v; v.u = ((uint_t)b) << 16;
  return v.f;
}

// ---------------- feat transpose (B,C,H,W)->(B,H,W,C) ----------------
__global__ __launch_bounds__(256) void transpose_feat(const float* __restrict__ src,
                                                      float* __restrict__ dst,
                                                      int C, int H, int W) {
  __shared__ float tile[32][33];
  int w0 = blockIdx.x * 32, c0 = blockIdx.y * 32;
  int b = blockIdx.z / H, h = blockIdx.z % H;
  int tx = threadIdx.x & 31, ty = threadIdx.x >> 5;
#pragma unroll
  for (int i = 0; i < 32; i += 8) {
    int c = c0 + ty + i, w = w0 + tx;
    float v = 0.f;
    if (c < C && w < W) v = src[((size_t)(b * C + c) * H + h) * W + w];
    tile[ty + i][tx] = v;
  }
  __syncthreads();
#pragma unroll
  for (int i = 0; i < 32; i += 8) {
    int w = w0 + ty + i, c = c0 + tx;
    if (c < C && w < W) dst[((size_t)(b * H + h) * W + w) * C + c] = tile[tx][ty + i];
  }
}

// ---------------- wd (o,i,2,2) -> wdT[tap][i][o] ----------------
__global__ __launch_bounds__(256) void transpose_wd(const float* __restrict__ wd,
                                                    float* __restrict__ wdT) {
  int idx = blockIdx.x * 256 + threadIdx.x;
  int o = idx & 255;
  int rest = idx >> 8;
  int i = rest & 255;
  int tap = rest >> 8;
  wdT[idx] = wd[((size_t)o * 256 + i) * 4 + tap];
}

// ---------------- conv weights (o,i,3,3) f32 -> [tap][o][i] bf16 ----------------
__global__ __launch_bounds__(256) void conv_wprep(const float* __restrict__ w0,
                                                  const float* __restrict__ w1,
                                                  const float* __restrict__ w2,
                                                  const float* __restrict__ w3,
                                                  ushort_t* __restrict__ dst) {
  int l = blockIdx.y;
  const float* w = (l == 0) ? w0 : (l == 1) ? w1 : (l == 2) ? w2 : w3;
  int idx = blockIdx.x * 256 + threadIdx.x;   // tap*65536 + o*256 + i
  int tap = idx >> 16;
  int rest = idx & 65535;
  int o = rest >> 8, i = rest & 255;
  dst[(size_t)l * 589824 + idx] = f2bf(w[((size_t)o * 256 + i) * 9 + tap]);
}

// ---------------- ROI align (channels-last feats) ----------------
__global__ __launch_bounds__(256) void roi_align_k(
    const float* __restrict__ t2, const float* __restrict__ t3,
    const float* __restrict__ t4, const float* __restrict__ t5,
    const float* __restrict__ boxes, const int* __restrict__ bidx,
    float* __restrict__ outp, int OUT, int CLAST) {
  int n = blockIdx.x, pix = blockIdx.y;
  int oy = pix / OUT, ox = pix % OUT;
  int c = threadIdx.x;
  float bx1 = boxes[n * 4 + 0], by1 = boxes[n * 4 + 1];
  float bx2 = boxes[n * 4 + 2], by2 = boxes[n * 4 + 3];
  float area = (bx2 - bx1) * (by2 - by1);
  float kf = floorf(4.0f + log2f(sqrtf(area) / 224.0f + 1e-6f));
  kf = fminf(fmaxf(kf, 2.0f), 5.0f);
  int lvl = (int)kf - 2;
  float scale = 0.25f / (float)(1 << lvl);
  const float* f = (lvl == 0) ? t2 : (lvl == 1) ? t3 : (lvl == 2) ? t4 : t5;
  int H = 200 >> lvl, W = 200 >> lvl;
  int b = bidx[n];
  float x1 = bx1 * scale, y1 = by1 * scale, x2 = bx2 * scale, y2 = by2 * scale;
  float rw = fmaxf(x2 - x1, 1.0f), rh = fmaxf(y2 - y1, 1.0f);
  int P = OUT * 2;
  float acc = 0.f;
#pragma unroll
  for (int sy = 0; sy < 2; ++sy) {
    float offy = ((float)(oy * 2 + sy) + 0.5f) / (float)P;
    float gy = fminf(fmaxf(y1 + offy * rh, 0.f), (float)(H - 1));
    int yy0 = (int)floorf(gy);
    int yy1 = min(yy0 + 1, H - 1);
    float ly = gy - (float)yy0;
#pragma unroll
    for (int sx = 0; sx < 2; ++sx) {
      float offx = ((float)(ox * 2 + sx) + 0.5f) / (float)P;
      float gx = fminf(fmaxf(x1 + offx * rw, 0.f), (float)(W - 1));
      int xx0 = (int)floorf(gx);
      int xx1 = min(xx0 + 1, W - 1);
      float lx = gx - (float)xx0;
      size_t base = (size_t)b * H * W * 256;
      float v00 = f[base + ((size_t)yy0 * W + xx0) * 256 + c];
      float v01 = f[base + ((size_t)yy0 * W + xx1) * 256 + c];
      float v10 = f[base + ((size_t)yy1 * W + xx0) * 256 + c];
      float v11 = f[base + ((size_t)yy1 * W + xx1) * 256 + c];
      acc += v00 * (1 - ly) * (1 - lx) + v01 * (1 - ly) * lx +
             v10 * ly * (1 - lx) + v11 * ly * lx;
    }
  }
  acc *= 0.25f;
  if (CLAST)
    ((ushort_t*)outp)[((size_t)n * OUT * OUT + pix) * 256 + c] = f2bf(acc);
  else
    outp[((size_t)n * 256 + c) * (OUT * OUT) + pix] = acc;
}

// ---------------- GEMM: C[s] partial = A(M,K) * B(N,K)^T over K-slice s ----------------
__global__ __launch_bounds__(256) void gemm_nt(const float* __restrict__ A,
                                               const float* __restrict__ B,
                                               float* __restrict__ C,
                                               int M, int N, int K) {
  __shared__ float As[32][33];
  __shared__ float Bs[32][33];
  int KS = gridDim.z;
  int kslice = K / KS;
  int k0 = blockIdx.z * kslice;
  int ib = blockIdx.x, jb = blockIdx.y;
  int tid = threadIdx.x;
  int tx = tid & 31, ty = tid >> 5;
  int ti = tid >> 4, tj = tid & 15;
  float a00 = 0, a01 = 0, a10 = 0, a11 = 0;
  const float* Ab = A + (size_t)(ib * 32) * K;
  const float* Bb = B + (size_t)(jb * 32) * K;
  for (int kc = 0; kc < kslice; kc += 32) {
    __syncthreads();
#pragma unroll
    for (int r = 0; r < 4; ++r) {
      As[ty + 8 * r][tx] = Ab[(size_t)(ty + 8 * r) * K + k0 + kc + tx];
      Bs[ty + 8 * r][tx] = Bb[(size_t)(ty + 8 * r) * K + k0 + kc + tx];
    }
    __syncthreads();
#pragma unroll
    for (int k = 0; k < 32; ++k) {
      float av0 = As[2 * ti][k], av1 = As[2 * ti + 1][k];
      float bv0 = Bs[2 * tj][k], bv1 = Bs[2 * tj + 1][k];
      a00 += av0 * bv0; a01 += av0 * bv1; a10 += av1 * bv0; a11 += av1 * bv1;
    }
  }
  size_t co = ((size_t)blockIdx.z * M + ib * 32) * N + jb * 32;
  C[co + (size_t)(2 * ti) * N + 2 * tj] = a00;
  C[co + (size_t)(2 * ti) * N + 2 * tj + 1] = a01;
  C[co + (size_t)(2 * ti + 1) * N + 2 * tj] = a10;
  C[co + (size_t)(2 * ti + 1) * N + 2 * tj + 1] = a11;
}

__global__ __launch_bounds__(256) void reduce_bias_relu(const float* __restrict__ pb,
                                                        const float* __restrict__ bias,
                                                        float* __restrict__ out,
                                                        int MN, int N, int S) {
  int idx = blockIdx.x * 256 + threadIdx.x;
  if (idx >= MN) return;
  float v = 0.f;
  for (int s = 0; s < S; ++s) v += pb[(size_t)s * MN + idx];
  v += bias[idx % N];
  out[idx] = fmaxf(v, 0.f);
}

// ---------------- cls/bbox head ----------------
__global__ __launch_bounds__(256) void head_kernel(const float* __restrict__ h2,
                                                   const float* __restrict__ Wc,
                                                   const float* __restrict__ bc,
                                                   const float* __restrict__ Wb,
                                                   const float* __restrict__ bb,
                                                   float* __restrict__ out) {
  int n = blockIdx.x;
  int tid = threadIdx.x;
  __shared__ float s[1024];
  __shared__ float red[10][4];
#pragma unroll
  for (int r = 0; r < 4; ++r) s[tid + 256 * r] = h2[(size_t)n * 1024 + tid + 256 * r];
  __syncthreads();
  for (int j = 0; j < 10; ++j) {
    const float* w = (j < 2) ? &Wc[j * 1024] : &Wb[(j - 2) * 1024];
    float v = 0.f;
#pragma unroll
    for (int r = 0; r < 4; ++r) v += s[tid + 256 * r] * w[tid + 256 * r];
#pragma unroll
    for (int off = 32; off > 0; off >>= 1) v += __shfl_down(v, off);
    if ((tid & 63) == 0) red[j][tid >> 6] = v;
  }
  __syncthreads();
  if (tid < 10) {
    float v = red[tid][0] + red[tid][1] + red[tid][2] + red[tid][3];
    if (tid < 2) out[n * 2 + tid] = v + bc[tid];
    else out[512 + n * 8 + (tid - 2)] = v + bb[tid - 2];
  }
}

// ---------------- conv3x3 via MFMA, bf16, one roi per block ----------------
// in: [n][196][256] bf16   wT: [9][256][256] bf16 ([tap][o][i])   out: bf16
// LDS image: zero-padded 16x16 grid, row r=(y+1)*16+(x+1), 264-short rows.
__global__ __launch_bounds__(512, 2) void conv3x3_mfma(
    const ushort_t* __restrict__ in, const ushort_t* __restrict__ wT,
    const float* __restrict__ bias, ushort_t* __restrict__ out) {
  __shared__ ushort_t simg[256 * 264];   // 135168 B
  __shared__ ushort_t swt[256 * 40];     // 20480 B
  int n = blockIdx.x;
  int tid = threadIdx.x;
  int lane15 = tid & 15;
  int hi = (tid >> 4) & 3;           // quarter-wave group
  int wid = tid >> 6;                // wave 0..7
  int mg = wid >> 1, ng = wid & 1;
  int mstart = (mg == 0) ? 0 : (1 + 3 * mg);   // 0,4,7,10
  int mcount = (mg == 0) ? 4 : 3;
  int ngbase = ng * 128;

  // zero image LDS
  for (int i = tid; i < 256 * 264 / 2; i += 512) ((uint_t*)simg)[i] = 0u;
  __syncthreads();
  // stage roi image (bf16 16B chunks) into padded grid
  for (int it = 0; it < 13; ++it) {
    int idx = it * 512 + tid;
    if (idx < 6272) {
      int px = idx >> 5, part = idx & 31;
      int y = px / 14, x = px - y * 14;
      int r = (y + 1) * 16 + (x + 1);
      *(short8*)&simg[r * 264 + part * 8] =
          *(const short8*)(in + ((size_t)n * 196 + px) * 256 + part * 8);
    }
  }
  // per-lane A row bases for this wave's M tiles
  int r0[4];
#pragma unroll
  for (int m = 0; m < 4; ++m) {
    int p = (mstart + m) * 16 + lane15;
    int y = p / 14, x = p - y * 14;
    r0[m] = (p < 196) ? (y + 1) * 16 + (x + 1) : 17;
  }
  // weight-slice fetch lanes: granules t and t+512 of the 16KB slice
  int g1 = tid, g2 = tid + 512;
  int n1 = g1 >> 2, s1 = g1 & 3;
  int n2 = g2 >> 2, s2 = g2 & 3;

  // prologue: fetch slice 0 and write it
  short8 pf0 = *(const short8*)(wT + (size_t)n1 * 256 + s1 * 8);
  short8 pf1 = *(const short8*)(wT + (size_t)n2 * 256 + s2 * 8);
  *(short8*)&swt[n1 * 40 + s1 * 8] = pf0;
  *(short8*)&swt[n2 * 40 + s2 * 8] = pf1;

  f32x4 acc[4][8];
#pragma unroll
  for (int m = 0; m < 4; ++m)
#pragma unroll
    for (int bt = 0; bt < 8; ++bt) acc[m][bt] = (f32x4)0.f;

  for (int it = 0; it < 72; ++it) {
    __syncthreads();   // swt slice `it` + (it==0: image) visible
    int tap = it >> 3, ks = it & 7;
    if (it < 71) {
      int nt = it + 1;
      int ntap = nt >> 3, nks = nt & 7;
      size_t sb = (size_t)ntap * 65536 + (size_t)nks * 32;
      pf0 = *(const short8*)(wT + sb + (size_t)n1 * 256 + s1 * 8);
      pf1 = *(const short8*)(wT + sb + (size_t)n2 * 256 + s2 * 8);
    }
    int dtap = ((tap / 3) - 1) * 16 + (tap % 3) - 1;
    short8 bfr[8];
#pragma unroll
    for (int bt = 0; bt < 8; ++bt)
      bfr[bt] = *(const short8*)&swt[(ngbase + bt * 16 + lane15) * 40 + hi * 8];
#pragma unroll
    for (int m = 0; m < 4; ++m) {
      if (m < mcount) {
        short8 af = *(const short8*)&simg[(r0[m] + dtap) * 264 + ks * 32 + hi * 8];
#pragma unroll
        for (int bt = 0; bt < 8; ++bt)
          acc[m][bt] = __builtin_amdgcn_mfma_f32_16x16x32_bf16(af, bfr[bt], acc[m][bt], 0, 0, 0);
      }
    }
    __syncthreads();   // all waves done reading swt
    if (it < 71) {
      *(short8*)&swt[n1 * 40 + s1 * 8] = pf0;
      *(short8*)&swt[n2 * 40 + s2 * 8] = pf1;
    }
  }
  // epilogue: bias + relu + bf16 store
#pragma unroll
  for (int m = 0; m < 4; ++m) {
    if (m < mcount) {
      int pbase = (mstart + m) * 16 + hi * 4;
#pragma unroll
      for (int bt = 0; bt < 8; ++bt) {
        int c = ngbase + bt * 16 + lane15;
        float bv = bias[c];
#pragma unroll
        for (int r = 0; r < 4; ++r) {
          int p = pbase + r;
          if (p < 196) {
            float v = fmaxf(acc[m][bt][r] + bv, 0.f);
            out[((size_t)n * 196 + p) * 256 + c] = f2bf(v);
          }
        }
      }
    }
  }
}

// ---------------- deconv 2x2 s2 + bias + relu + 1x1 conv to 2ch (fused) ----------------
__global__ __launch_bounds__(256) void deconv_mask(const ushort_t* __restrict__ in,  // bf16 [n][196][256]
                                                   const float* __restrict__ wdT,    // [tap][i][o]
                                                   const float* __restrict__ bd,
                                                   const float* __restrict__ wm5,
                                                   const float* __restrict__ bm5,
                                                   float* __restrict__ outp) {
  int n = blockIdx.x, iy = blockIdx.y;
  int o = threadIdx.x;
  __shared__ float s_in[14 * 256];
  __shared__ float s_red[112][4];
#pragma unroll
  for (int rr = 0; rr < 2; ++rr) {
    int slot = rr * 256 + threadIdx.x;   // 448 chunks of 8 bf16
    if (slot < 448) {
      short8 v = *(const short8*)(in + ((size_t)n * 196 + iy * 14) * 256 + slot * 8);
#pragma unroll
      for (int j = 0; j < 8; ++j) s_in[slot * 8 + j] = bf2f((ushort_t)v[j]);
    }
  }
  __syncthreads();
  float acc[4][14];
#pragma unroll
  for (int t = 0; t < 4; ++t)
#pragma unroll
    for (int ix = 0; ix < 14; ++ix) acc[t][ix] = 0.f;
#pragma unroll 4
  for (int i = 0; i < 256; ++i) {
    float si[14];
#pragma unroll
    for (int ix = 0; ix < 14; ++ix) si[ix] = s_in[ix * 256 + i];
#pragma unroll
    for (int tap = 0; tap < 4; ++tap) {
      float wv = wdT[((size_t)tap * 256 + i) * 256 + o];
#pragma unroll
      for (int ix = 0; ix < 14; ++ix) acc[tap][ix] += si[ix] * wv;
    }
  }
  float bdv = bd[o];
  float w50 = wm5[o], w51 = wm5[256 + o];
  int lane = threadIdx.x & 63, wid = threadIdx.x >> 6;
#pragma unroll
  for (int tap = 0; tap < 4; ++tap) {
#pragma unroll
    for (int ix = 0; ix < 14; ++ix) {
      float rr = fmaxf(acc[tap][ix] + bdv, 0.f);
      float p0 = rr * w50, p1 = rr * w51;
#pragma unroll
      for (int off = 1; off < 64; off <<= 1) {
        p0 += __shfl_xor(p0, off);
        p1 += __shfl_xor(p1, off);
      }
      if (lane == 0) {
        s_red[(tap * 14 + ix) * 2 + 0][wid] = p0;
        s_red[(tap * 14 + ix) * 2 + 1][wid] = p1;
      }
    }
  }
  __syncthreads();
  if (threadIdx.x < 112) {
    int pair = threadIdx.x >> 1, k = threadIdx.x & 1;
    float v = s_red[pair * 2 + k][0] + s_red[pair * 2 + k][1] +
              s_red[pair * 2 + k][2] + s_red[pair * 2 + k][3] + bm5[k];
    int tap = pair / 14, ix = pair % 14;
    int ky = tap >> 1, kx = tap & 1;
    int y = 2 * iy + 1 - ky, x = 2 * ix + 1 - kx;
    outp[2560 + (size_t)n * 1568 + k * 784 + y * 28 + x] = v;
  }
}

// ---------------- launch ----------------
extern "C" void kernel_launch(void* const* d_in, const int* in_sizes, int n_in,
                              void* d_out, int out_size, void* d_ws, size_t ws_size,
                              hipStream_t stream) {
  const float* f2 = (const float*)d_in[0];
  const float* f3 = (const float*)d_in[1];
  const float* f4 = (const float*)d_in[2];
  const float* f5 = (const float*)d_in[3];
  const float* boxes = (const float*)d_in[4];
  const int* bidx = (const int*)d_in[5];
  const float* W1 = (const float*)d_in[6];
  const float* b1 = (const float*)d_in[7];
  const float* W2 = (const float*)d_in[8];
  const float* b2 = (const float*)d_in[9];
  const float* Wc = (const float*)d_in[10];
  const float* bc = (const float*)d_in[11];
  const float* Wb = (const float*)d_in[12];
  const float* bb = (const float*)d_in[13];
  const float* wd = (const float*)d_in[14];
  const float* bd = (const float*)d_in[15];
  const float* wm5 = (const float*)d_in[16];
  const float* bm5 = (const float*)d_in[17];
  const float* wm[4] = {(const float*)d_in[18], (const float*)d_in[20],
                        (const float*)d_in[22], (const float*)d_in[24]};
  const float* bm[4] = {(const float*)d_in[19], (const float*)d_in[21],
                        (const float*)d_in[23], (const float*)d_in[25]};
  char* ws = (char*)d_ws;
  float* ftr2 = (float*)(ws + OFF_FTR2);
  float* ftr3 = (float*)(ws + OFF_FTR3);
  float* ftr4 = (float*)(ws + OFF_FTR4);
  float* ftr5 = (float*)(ws + OFF_FTR5);
  float* p7 = (float*)(ws + OFF_P7);
  float* h1 = (float*)(ws + OFF_H1);
  float* h2 = (float*)(ws + OFF_H2);
  float* pbuf = (float*)(ws + OFF_PB);
  float* wdT = (float*)(ws + OFF_WDT);
  ushort_t* mAb = (ushort_t*)(ws + OFF_MA);
  ushort_t* mBb = (ushort_t*)(ws + OFF_MB);
  ushort_t* wTl = (ushort_t*)(ws + OFF_WT);
  float* out = (float*)d_out;

  // feats -> channels-last
  transpose_feat<<<dim3(7, 8, 400), 256, 0, stream>>>(f2, ftr2, 256, 200, 200);
  transpose_feat<<<dim3(4, 8, 200), 256, 0, stream>>>(f3, ftr3, 256, 100, 100);
  transpose_feat<<<dim3(2, 8, 100), 256, 0, stream>>>(f4, ftr4, 256, 50, 50);
  transpose_feat<<<dim3(1, 8, 50), 256, 0, stream>>>(f5, ftr5, 256, 25, 25);
  transpose_wd<<<1024, 256, 0, stream>>>(wd, wdT);
  conv_wprep<<<dim3(2304, 4), 256, 0, stream>>>(wm[0], wm[1], wm[2], wm[3], wTl);

  // ROI align
  roi_align_k<<<dim3(256, 49), 256, 0, stream>>>(ftr2, ftr3, ftr4, ftr5, boxes,
                                                 bidx, p7, 7, 0);
  roi_align_k<<<dim3(256, 196), 256, 0, stream>>>(ftr2, ftr3, ftr4, ftr5, boxes,
                                                  bidx, (float*)mAb, 14, 1);

  // FC head
  gemm_nt<<<dim3(8, 32, 4), 256, 0, stream>>>(p7, W1, pbuf, 256, 1024, 12544);
  reduce_bias_relu<<<1024, 256, 0, stream>>>(pbuf, b1, h1, 262144, 1024, 4);
  gemm_nt<<<dim3(8, 32, 1), 256, 0, stream>>>(h1, W2, pbuf, 256, 1024, 1024);
  reduce_bias_relu<<<1024, 256, 0, stream>>>(pbuf, b2, h2, 262144, 1024, 1);
  head_kernel<<<256, 256, 0, stream>>>(h2, Wc, bc, Wb, bb, out);

  // mask head (bf16 MFMA convs)
  conv3x3_mfma<<<256, 512, 0, stream>>>(mAb, wTl + 0 * 589824, bm[0], mBb);
  conv3x3_mfma<<<256, 512, 0, stream>>>(mBb, wTl + 1 * 589824, bm[1], mAb);
  conv3x3_mfma<<<256, 512, 0, stream>>>(mAb, wTl + 2 * 589824, bm[2], mBb);
  conv3x3_mfma<<<256, 512, 0, stream>>>(mBb, wTl + 3 * 589824, bm[3], mAb);
  deconv_mask<<<dim3(256, 14), 256, 0, stream>>>(mAb, wdT, bd, wm5, bm5, out);
}

// Round 3
// 801.357 us; speedup vs baseline: 20.9472x; 1.4147x over previous
//
#include <hip/hip_runtime.h>
#include <math.h>

// ---------------- sizes ----------------
// inputs: 0 f2(2,256,200,200) 1 f3(2,256,100,100) 2 f4(2,256,50,50) 3 f5(2,256,25,25)
// 4 boxes(256,4) 5 batch_idx(256) 6 W1(1024,12544) 7 b1 8 W2(1024,1024) 9 b2
// 10 Wc(2,1024) 11 bc 12 Wb(8,1024) 13 bb 14 wd(256,256,2,2) 15 bd 16 wm5(2,256,1,1) 17 bm5
// 18 wm1 19 bm1 20 wm2 21 bm2 22 wm3 23 bm3 24 wm4 25 bm4
// out: cls(256,2) | bbox(256,8) | mask(256,2,28,28)

typedef __attribute__((ext_vector_type(8))) short short8;
typedef __attribute__((ext_vector_type(4))) float f32x4;
typedef unsigned short ushort_t;
typedef unsigned int uint_t;

// ws offsets (bytes)
#define OFF_FTR2 0ull
#define OFF_FTR3 81920000ull
#define OFF_FTR4 102400000ull
#define OFF_FTR5 107520000ull
#define OFF_P7   108800000ull
#define OFF_H1   121645056ull
#define OFF_H2   122693632ull
#define OFF_PB   123742208ull
#define OFF_WDT  127936512ull   // bf16 [4][256 o][256 i]: 524,288 B
#define OFF_MA   128985088ull   // bf16 [n][196][256]: 25,690,112 B
#define OFF_WT   155199488ull   // bf16 [4][9][256][256]: 4,718,592 B
#define OFF_MB   0ull           // aliases ftr2 (dead after roi-align)

__device__ inline ushort_t f2bf(float f) {
  union { float f; uint_t u; } v; v.f = f;
  uint_t r = (v.u + 0x7fffu + ((v.u >> 16) & 1u)) >> 16;
  return (ushort_t)r;
}
__device__ inline float bf2f(ushort_t b) {
  union { uint_t u; float f; } v; v.u = ((uint_t)b) << 16;
  return v.f;
}

// ---------------- feat transpose (B,C,H,W)->(B,H,W,C) ----------------
__global__ __launch_bounds__(256) void transpose_feat(const float* __restrict__ src,
                                                      float* __restrict__ dst,
                                                      int C, int H, int W) {
  __shared__ float tile[32][33];
  int w0 = blockIdx.x * 32, c0 = blockIdx.y * 32;
  int b = blockIdx.z / H, h = blockIdx.z % H;
  int tx = threadIdx.x & 31, ty = threadIdx.x >> 5;
#pragma unroll
  for (int i = 0; i < 32; i += 8) {
    int c = c0 + ty + i, w = w0 + tx;
    float v = 0.f;
    if (c < C && w < W) v = src[((size_t)(b * C + c) * H + h) * W + w];
    tile[ty + i][tx] = v;
  }
  __syncthreads();
#pragma unroll
  for (int i = 0; i < 32; i += 8) {
    int w = w0 + ty + i, c = c0 + tx;
    if (c < C && w < W) dst[((size_t)(b * H + h) * W + w) * C + c] = tile[tx][ty + i];
  }
}

// ---------------- wd (o,i,2,2) f32 -> bf16 [tap][o][i] ----------------
__global__ __launch_bounds__(256) void wd_prep(const float* __restrict__ wd,
                                               ushort_t* __restrict__ dst) {
  int idx = blockIdx.x * 256 + threadIdx.x;   // tap*65536 + o*256 + i
  int tap = idx >> 16;
  int rest = idx & 65535;
  int o = rest >> 8, i = rest & 255;
  dst[idx] = f2bf(wd[((size_t)o * 256 + i) * 4 + tap]);
}

// ---------------- conv weights (o,i,3,3) f32 -> [tap][o][i] bf16 ----------------
__global__ __launch_bounds__(256) void conv_wprep(const float* __restrict__ w0,
                                                  const float* __restrict__ w1,
                                                  const float* __restrict__ w2,
                                                  const float* __restrict__ w3,
                                                  ushort_t* __restrict__ dst) {
  int l = blockIdx.y;
  const float* w = (l == 0) ? w0 : (l == 1) ? w1 : (l == 2) ? w2 : w3;
  int idx = blockIdx.x * 256 + threadIdx.x;   // tap*65536 + o*256 + i
  int tap = idx >> 16;
  int rest = idx & 65535;
  int o = rest >> 8, i = rest & 255;
  dst[(size_t)l * 589824 + idx] = f2bf(w[((size_t)o * 256 + i) * 9 + tap]);
}

// ---------------- ROI align (channels-last feats) ----------------
__global__ __launch_bounds__(256) void roi_align_k(
    const float* __restrict__ t2, const float* __restrict__ t3,
    const float* __restrict__ t4, const float* __restrict__ t5,
    const float* __restrict__ boxes, const int* __restrict__ bidx,
    float* __restrict__ outp, int OUT, int CLAST) {
  int n = blockIdx.x, pix = blockIdx.y;
  int oy = pix / OUT, ox = pix % OUT;
  int c = threadIdx.x;
  float bx1 = boxes[n * 4 + 0], by1 = boxes[n * 4 + 1];
  float bx2 = boxes[n * 4 + 2], by2 = boxes[n * 4 + 3];
  float area = (bx2 - bx1) * (by2 - by1);
  float kf = floorf(4.0f + log2f(sqrtf(area) / 224.0f + 1e-6f));
  kf = fminf(fmaxf(kf, 2.0f), 5.0f);
  int lvl = (int)kf - 2;
  float scale = 0.25f / (float)(1 << lvl);
  const float* f = (lvl == 0) ? t2 : (lvl == 1) ? t3 : (lvl == 2) ? t4 : t5;
  int H = 200 >> lvl, W = 200 >> lvl;
  int b = bidx[n];
  float x1 = bx1 * scale, y1 = by1 * scale, x2 = bx2 * scale, y2 = by2 * scale;
  float rw = fmaxf(x2 - x1, 1.0f), rh = fmaxf(y2 - y1, 1.0f);
  int P = OUT * 2;
  float acc = 0.f;
#pragma unroll
  for (int sy = 0; sy < 2; ++sy) {
    float offy = ((float)(oy * 2 + sy) + 0.5f) / (float)P;
    float gy = fminf(fmaxf(y1 + offy * rh, 0.f), (float)(H - 1));
    int yy0 = (int)floorf(gy);
    int yy1 = min(yy0 + 1, H - 1);
    float ly = gy - (float)yy0;
#pragma unroll
    for (int sx = 0; sx < 2; ++sx) {
      float offx = ((float)(ox * 2 + sx) + 0.5f) / (float)P;
      float gx = fminf(fmaxf(x1 + offx * rw, 0.f), (float)(W - 1));
      int xx0 = (int)floorf(gx);
      int xx1 = min(xx0 + 1, W - 1);
      float lx = gx - (float)xx0;
      size_t base = (size_t)b * H * W * 256;
      float v00 = f[base + ((size_t)yy0 * W + xx0) * 256 + c];
      float v01 = f[base + ((size_t)yy0 * W + xx1) * 256 + c];
      float v10 = f[base + ((size_t)yy1 * W + xx0) * 256 + c];
      float v11 = f[base + ((size_t)yy1 * W + xx1) * 256 + c];
      acc += v00 * (1 - ly) * (1 - lx) + v01 * (1 - ly) * lx +
             v10 * ly * (1 - lx) + v11 * ly * lx;
    }
  }
  acc *= 0.25f;
  if (CLAST)
    ((ushort_t*)outp)[((size_t)n * OUT * OUT + pix) * 256 + c] = f2bf(acc);
  else
    outp[((size_t)n * 256 + c) * (OUT * OUT) + pix] = acc;
}

// ---------------- GEMM: C[s] partial = A(M,K) * B(N,K)^T over K-slice s ----------------
__global__ __launch_bounds__(256) void gemm_nt(const float* __restrict__ A,
                                               const float* __restrict__ B,
                                               float* __restrict__ C,
                                               int M, int N, int K) {
  __shared__ float As[32][33];
  __shared__ float Bs[32][33];
  int KS = gridDim.z;
  int kslice = K / KS;
  int k0 = blockIdx.z * kslice;
  int ib = blockIdx.x, jb = blockIdx.y;
  int tid = threadIdx.x;
  int tx = tid & 31, ty = tid >> 5;
  int ti = tid >> 4, tj = tid & 15;
  float a00 = 0, a01 = 0, a10 = 0, a11 = 0;
  const float* Ab = A + (size_t)(ib * 32) * K;
  const float* Bb = B + (size_t)(jb * 32) * K;
  for (int kc = 0; kc < kslice; kc += 32) {
    __syncthreads();
#pragma unroll
    for (int r = 0; r < 4; ++r) {
      As[ty + 8 * r][tx] = Ab[(size_t)(ty + 8 * r) * K + k0 + kc + tx];
      Bs[ty + 8 * r][tx] = Bb[(size_t)(ty + 8 * r) * K + k0 + kc + tx];
    }
    __syncthreads();
#pragma unroll
    for (int k = 0; k < 32; ++k) {
      float av0 = As[2 * ti][k], av1 = As[2 * ti + 1][k];
      float bv0 = Bs[2 * tj][k], bv1 = Bs[2 * tj + 1][k];
      a00 += av0 * bv0; a01 += av0 * bv1; a10 += av1 * bv0; a11 += av1 * bv1;
    }
  }
  size_t co = ((size_t)blockIdx.z * M + ib * 32) * N + jb * 32;
  C[co + (size_t)(2 * ti) * N + 2 * tj] = a00;
  C[co + (size_t)(2 * ti) * N + 2 * tj + 1] = a01;
  C[co + (size_t)(2 * ti + 1) * N + 2 * tj] = a10;
  C[co + (size_t)(2 * ti + 1) * N + 2 * tj + 1] = a11;
}

__global__ __launch_bounds__(256) void reduce_bias_relu(const float* __restrict__ pb,
                                                        const float* __restrict__ bias,
                                                        float* __restrict__ out,
                                                        int MN, int N, int S) {
  int idx = blockIdx.x * 256 + threadIdx.x;
  if (idx >= MN) return;
  float v = 0.f;
  for (int s = 0; s < S; ++s) v += pb[(size_t)s * MN + idx];
  v += bias[idx % N];
  out[idx] = fmaxf(v, 0.f);
}

// ---------------- cls/bbox head ----------------
__global__ __launch_bounds__(256) void head_kernel(const float* __restrict__ h2,
                                                   const float* __restrict__ Wc,
                                                   const float* __restrict__ bc,
                                                   const float* __restrict__ Wb,
                                                   const float* __restrict__ bb,
                                                   float* __restrict__ out) {
  int n = blockIdx.x;
  int tid = threadIdx.x;
  __shared__ float s[1024];
  __shared__ float red[10][4];
#pragma unroll
  for (int r = 0; r < 4; ++r) s[tid + 256 * r] = h2[(size_t)n * 1024 + tid + 256 * r];
  __syncthreads();
  for (int j = 0; j < 10; ++j) {
    const float* w = (j < 2) ? &Wc[j * 1024] : &Wb[(j - 2) * 1024];
    float v = 0.f;
#pragma unroll
    for (int r = 0; r < 4; ++r) v += s[tid + 256 * r] * w[tid + 256 * r];
#pragma unroll
    for (int off = 32; off > 0; off >>= 1) v += __shfl_down(v, off);
    if ((tid & 63) == 0) red[j][tid >> 6] = v;
  }
  __syncthreads();
  if (tid < 10) {
    float v = red[tid][0] + red[tid][1] + red[tid][2] + red[tid][3];
    if (tid < 2) out[n * 2 + tid] = v + bc[tid];
    else out[512 + n * 8 + (tid - 2)] = v + bb[tid - 2];
  }
}

// ---------------- conv3x3 via MFMA, bf16, one roi per block ----------------
__global__ __launch_bounds__(512, 2) void conv3x3_mfma(
    const ushort_t* __restrict__ in, const ushort_t* __restrict__ wT,
    const float* __restrict__ bias, ushort_t* __restrict__ out) {
  __shared__ ushort_t simg[256 * 264];   // 135168 B
  __shared__ ushort_t swt[256 * 40];     // 20480 B
  int n = blockIdx.x;
  int tid = threadIdx.x;
  int lane15 = tid & 15;
  int hi = (tid >> 4) & 3;
  int wid = tid >> 6;
  int mg = wid >> 1, ng = wid & 1;
  int mstart = (mg == 0) ? 0 : (1 + 3 * mg);
  int mcount = (mg == 0) ? 4 : 3;
  int ngbase = ng * 128;

  for (int i = tid; i < 256 * 264 / 2; i += 512) ((uint_t*)simg)[i] = 0u;
  __syncthreads();
  for (int it = 0; it < 13; ++it) {
    int idx = it * 512 + tid;
    if (idx < 6272) {
      int px = idx >> 5, part = idx & 31;
      int y = px / 14, x = px - y * 14;
      int r = (y + 1) * 16 + (x + 1);
      *(short8*)&simg[r * 264 + part * 8] =
          *(const short8*)(in + ((size_t)n * 196 + px) * 256 + part * 8);
    }
  }
  int r0[4];
#pragma unroll
  for (int m = 0; m < 4; ++m) {
    int p = (mstart + m) * 16 + lane15;
    int y = p / 14, x = p - y * 14;
    r0[m] = (p < 196) ? (y + 1) * 16 + (x + 1) : 17;
  }
  int g1 = tid, g2 = tid + 512;
  int n1 = g1 >> 2, s1 = g1 & 3;
  int n2 = g2 >> 2, s2 = g2 & 3;

  short8 pf0 = *(const short8*)(wT + (size_t)n1 * 256 + s1 * 8);
  short8 pf1 = *(const short8*)(wT + (size_t)n2 * 256 + s2 * 8);
  *(short8*)&swt[n1 * 40 + s1 * 8] = pf0;
  *(short8*)&swt[n2 * 40 + s2 * 8] = pf1;

  f32x4 acc[4][8];
#pragma unroll
  for (int m = 0; m < 4; ++m)
#pragma unroll
    for (int bt = 0; bt < 8; ++bt) acc[m][bt] = (f32x4)0.f;

  for (int it = 0; it < 72; ++it) {
    __syncthreads();
    int tap = it >> 3, ks = it & 7;
    if (it < 71) {
      int nt = it + 1;
      int ntap = nt >> 3, nks = nt & 7;
      size_t sb = (size_t)ntap * 65536 + (size_t)nks * 32;
      pf0 = *(const short8*)(wT + sb + (size_t)n1 * 256 + s1 * 8);
      pf1 = *(const short8*)(wT + sb + (size_t)n2 * 256 + s2 * 8);
    }
    int dtap = ((tap / 3) - 1) * 16 + (tap % 3) - 1;
    short8 bfr[8];
#pragma unroll
    for (int bt = 0; bt < 8; ++bt)
      bfr[bt] = *(const short8*)&swt[(ngbase + bt * 16 + lane15) * 40 + hi * 8];
#pragma unroll
    for (int m = 0; m < 4; ++m) {
      if (m < mcount) {
        short8 af = *(const short8*)&simg[(r0[m] + dtap) * 264 + ks * 32 + hi * 8];
#pragma unroll
        for (int bt = 0; bt < 8; ++bt)
          acc[m][bt] = __builtin_amdgcn_mfma_f32_16x16x32_bf16(af, bfr[bt], acc[m][bt], 0, 0, 0);
      }
    }
    __syncthreads();
    if (it < 71) {
      *(short8*)&swt[n1 * 40 + s1 * 8] = pf0;
      *(short8*)&swt[n2 * 40 + s2 * 8] = pf1;
    }
  }
#pragma unroll
  for (int m = 0; m < 4; ++m) {
    if (m < mcount) {
      int pbase = (mstart + m) * 16 + hi * 4;
#pragma unroll
      for (int bt = 0; bt < 8; ++bt) {
        int c = ngbase + bt * 16 + lane15;
        float bv = bias[c];
#pragma unroll
        for (int r = 0; r < 4; ++r) {
          int p = pbase + r;
          if (p < 196) {
            float v = fmaxf(acc[m][bt][r] + bv, 0.f);
            out[((size_t)n * 196 + p) * 256 + c] = f2bf(v);
          }
        }
      }
    }
  }
}

// ---------------- deconv 2x2 s2 + bias + relu + 1x1 conv, fused, MFMA ----------------
// in: bf16 [n][196][256]   wdT: bf16 [tap][o][i]   out logits -> d_out
__global__ __launch_bounds__(512, 2) void deconv_mask_mfma(
    const ushort_t* __restrict__ in, const ushort_t* __restrict__ wdT,
    const float* __restrict__ bd, const float* __restrict__ wm5,
    const float* __restrict__ bm5, float* __restrict__ outp) {
  __shared__ ushort_t simg[208 * 264];   // 109824 B
  __shared__ ushort_t swt[256 * 40];     // 20480 B
  __shared__ float s_red[784];           // [p][k][ng]
  int n = blockIdx.x;
  int tid = threadIdx.x;
  int lane15 = tid & 15;
  int hi = (tid >> 4) & 3;
  int wid = tid >> 6;
  int mg = wid >> 1, ng = wid & 1;
  int mstart = (mg == 0) ? 0 : (1 + 3 * mg);   // tiles 0-3,4-6,7-9,10-12
  int mcount = (mg == 0) ? 4 : 3;
  int ngbase = ng * 128;

  // stage image rows 0..195; zero pad rows 196..207
  for (int it = 0; it < 13; ++it) {
    int idx = it * 512 + tid;
    if (idx < 6272) {
      int px = idx >> 5, part = idx & 31;
      *(short8*)&simg[px * 264 + part * 8] =
          *(const short8*)(in + ((size_t)n * 196 + px) * 256 + part * 8);
    }
  }
  for (int i = tid; i < 12 * 264 / 2; i += 512) ((uint_t*)&simg[196 * 264])[i] = 0u;

  // per-lane constants
  float bdv[8], w0v[8], w1v[8];
#pragma unroll
  for (int bt = 0; bt < 8; ++bt) {
    int c = ngbase + bt * 16 + lane15;
    bdv[bt] = bd[c];
    w0v[bt] = wm5[c];
    w1v[bt] = wm5[256 + c];
  }
  int rowb[4];
#pragma unroll
  for (int m = 0; m < 4; ++m) rowb[m] = ((mstart + m) * 16 + lane15) * 264;

  int g1 = tid, g2 = tid + 512;
  int n1 = g1 >> 2, s1 = g1 & 3;
  int n2 = g2 >> 2, s2 = g2 & 3;

  // prologue: fetch slice 0
  short8 pf0 = *(const short8*)(wdT + (size_t)n1 * 256 + s1 * 8);
  short8 pf1 = *(const short8*)(wdT + (size_t)n2 * 256 + s2 * 8);
  *(short8*)&swt[n1 * 40 + s1 * 8] = pf0;
  *(short8*)&swt[n2 * 40 + s2 * 8] = pf1;

  f32x4 acc[4][8];
#pragma unroll
  for (int m = 0; m < 4; ++m)
#pragma unroll
    for (int bt = 0; bt < 8; ++bt) acc[m][bt] = (f32x4)0.f;

  for (int g = 0; g < 32; ++g) {
    __syncthreads();   // slice g (and image on g==0) visible
    int tap = g >> 3, ks = g & 7;
    if (g < 31) {
      int ng_ = g + 1;
      size_t sb = (size_t)(ng_ >> 3) * 65536 + (size_t)(ng_ & 7) * 32;
      pf0 = *(const short8*)(wdT + sb + (size_t)n1 * 256 + s1 * 8);
      pf1 = *(const short8*)(wdT + sb + (size_t)n2 * 256 + s2 * 8);
    }
    short8 bfr[8];
#pragma unroll
    for (int bt = 0; bt < 8; ++bt)
      bfr[bt] = *(const short8*)&swt[(ngbase + bt * 16 + lane15) * 40 + hi * 8];
#pragma unroll
    for (int m = 0; m < 4; ++m) {
      if (m < mcount) {
        short8 af = *(const short8*)&simg[rowb[m] + ks * 32 + hi * 8];
#pragma unroll
        for (int bt = 0; bt < 8; ++bt)
          acc[m][bt] = __builtin_amdgcn_mfma_f32_16x16x32_bf16(af, bfr[bt], acc[m][bt], 0, 0, 0);
      }
    }
    __syncthreads();   // reads of swt done
    if (g < 31) {
      *(short8*)&swt[n1 * 40 + s1 * 8] = pf0;
      *(short8*)&swt[n2 * 40 + s2 * 8] = pf1;
    }
    if ((g & 7) == 7) {
      // ---- epilogue for this tap ----
#pragma unroll
      for (int m = 0; m < 4; ++m) {
        if (m < mcount) {
#pragma unroll
          for (int r = 0; r < 4; ++r) {
            int p = (mstart + m) * 16 + hi * 4 + r;
            float v0 = 0.f, v1 = 0.f;
#pragma unroll
            for (int bt = 0; bt < 8; ++bt) {
              float t = fmaxf(acc[m][bt][r] + bdv[bt], 0.f);
              v0 += t * w0v[bt];
              v1 += t * w1v[bt];
            }
#pragma unroll
            for (int off = 1; off < 16; off <<= 1) {
              v0 += __shfl_xor(v0, off);
              v1 += __shfl_xor(v1, off);
            }
            if (lane15 == 0 && p < 196) {
              s_red[(p * 2 + 0) * 2 + ng] = v0;
              s_red[(p * 2 + 1) * 2 + ng] = v1;
            }
          }
        }
      }
      __syncthreads();
      if (tid < 392) {
        int p = tid >> 1, k = tid & 1;
        float v = s_red[(p * 2 + k) * 2 + 0] + s_red[(p * 2 + k) * 2 + 1] + bm5[k];
        int iy = p / 14, ix = p - iy * 14;
        int ky = tap >> 1, kx = tap & 1;
        int y = 2 * iy + 1 - ky, x = 2 * ix + 1 - kx;
        outp[2560 + (size_t)n * 1568 + k * 784 + y * 28 + x] = v;
      }
      // reset acc for next tap
#pragma unroll
      for (int m = 0; m < 4; ++m)
#pragma unroll
        for (int bt = 0; bt < 8; ++bt) acc[m][bt] = (f32x4)0.f;
    }
  }
}

// ---------------- launch ----------------
extern "C" void kernel_launch(void* const* d_in, const int* in_sizes, int n_in,
                              void* d_out, int out_size, void* d_ws, size_t ws_size,
                              hipStream_t stream) {
  const float* f2 = (const float*)d_in[0];
  const float* f3 = (const float*)d_in[1];
  const float* f4 = (const float*)d_in[2];
  const float* f5 = (const float*)d_in[3];
  const float* boxes = (const float*)d_in[4];
  const int* bidx = (const int*)d_in[5];
  const float* W1 = (const float*)d_in[6];
  const float* b1 = (const float*)d_in[7];
  const float* W2 = (const float*)d_in[8];
  const float* b2 = (const float*)d_in[9];
  const float* Wc = (const float*)d_in[10];
  const float* bc = (const float*)d_in[11];
  const float* Wb = (const float*)d_in[12];
  const float* bb = (const float*)d_in[13];
  const float* wd = (const float*)d_in[14];
  const float* bd = (const float*)d_in[15];
  const float* wm5 = (const float*)d_in[16];
  const float* bm5 = (const float*)d_in[17];
  const float* wm[4] = {(const float*)d_in[18], (const float*)d_in[20],
                        (const float*)d_in[22], (const float*)d_in[24]};
  const float* bm[4] = {(const float*)d_in[19], (const float*)d_in[21],
                        (const float*)d_in[23], (const float*)d_in[25]};
  char* ws = (char*)d_ws;
  float* ftr2 = (float*)(ws + OFF_FTR2);
  float* ftr3 = (float*)(ws + OFF_FTR3);
  float* ftr4 = (float*)(ws + OFF_FTR4);
  float* ftr5 = (float*)(ws + OFF_FTR5);
  float* p7 = (float*)(ws + OFF_P7);
  float* h1 = (float*)(ws + OFF_H1);
  float* h2 = (float*)(ws + OFF_H2);
  float* pbuf = (float*)(ws + OFF_PB);
  ushort_t* wdTb = (ushort_t*)(ws + OFF_WDT);
  ushort_t* mAb = (ushort_t*)(ws + OFF_MA);
  ushort_t* mBb = (ushort_t*)(ws + OFF_MB);
  ushort_t* wTl = (ushort_t*)(ws + OFF_WT);
  float* out = (float*)d_out;

  // feats -> channels-last
  transpose_feat<<<dim3(7, 8, 400), 256, 0, stream>>>(f2, ftr2, 256, 200, 200);
  transpose_feat<<<dim3(4, 8, 200), 256, 0, stream>>>(f3, ftr3, 256, 100, 100);
  transpose_feat<<<dim3(2, 8, 100), 256, 0, stream>>>(f4, ftr4, 256, 50, 50);
  transpose_feat<<<dim3(1, 8, 50), 256, 0, stream>>>(f5, ftr5, 256, 25, 25);
  wd_prep<<<1024, 256, 0, stream>>>(wd, wdTb);
  conv_wprep<<<dim3(2304, 4), 256, 0, stream>>>(wm[0], wm[1], wm[2], wm[3], wTl);

  // ROI align
  roi_align_k<<<dim3(256, 49), 256, 0, stream>>>(ftr2, ftr3, ftr4, ftr5, boxes,
                                                 bidx, p7, 7, 0);
  roi_align_k<<<dim3(256, 196), 256, 0, stream>>>(ftr2, ftr3, ftr4, ftr5, boxes,
                                                  bidx, (float*)mAb, 14, 1);

  // FC head
  gemm_nt<<<dim3(8, 32, 4), 256, 0, stream>>>(p7, W1, pbuf, 256, 1024, 12544);
  reduce_bias_relu<<<1024, 256, 0, stream>>>(pbuf, b1, h1, 262144, 1024, 4);
  gemm_nt<<<dim3(8, 32, 1), 256, 0, stream>>>(h1, W2, pbuf, 256, 1024, 1024);
  reduce_bias_relu<<<1024, 256, 0, stream>>>(pbuf, b2, h2, 262144, 1024, 1);
  head_kernel<<<256, 256, 0, stream>>>(h2, Wc, bc, Wb, bb, out);

  // mask head (bf16 MFMA convs)
  conv3x3_mfma<<<256, 512, 0, stream>>>(mAb, wTl + 0 * 589824, bm[0], mBb);
  conv3x3_mfma<<<256, 512, 0, stream>>>(mBb, wTl + 1 * 589824, bm[1], mAb);
  conv3x3_mfma<<<256, 512, 0, stream>>>(mAb, wTl + 2 * 589824, bm[2], mBb);
  conv3x3_mfma<<<256, 512, 0, stream>>>(mBb, wTl + 3 * 589824, bm[3], mAb);
  deconv_mask_mfma<<<256, 512, 0, stream>>>(mAb, wdTb, bd, wm5, bm5, out);
}

// Round 4
// 615.596 us; speedup vs baseline: 27.2682x; 1.3018x over previous
//
#include <hip/hip_runtime.h>
#include <math.h>

// ---------------- sizes ----------------
// inputs: 0 f2(2,256,200,200) 1 f3(2,256,100,100) 2 f4(2,256,50,50) 3 f5(2,256,25,25)
// 4 boxes(256,4) 5 batch_idx(256) 6 W1(1024,12544) 7 b1 8 W2(1024,1024) 9 b2
// 10 Wc(2,1024) 11 bc 12 Wb(8,1024) 13 bb 14 wd(256,256,2,2) 15 bd 16 wm5(2,256,1,1) 17 bm5
// 18 wm1 19 bm1 20 wm2 21 bm2 22 wm3 23 bm3 24 wm4 25 bm4
// out: cls(256,2) | bbox(256,8) | mask(256,2,28,28)

typedef __attribute__((ext_vector_type(8))) short short8;
typedef __attribute__((ext_vector_type(4))) float f32x4;
typedef unsigned short ushort_t;
typedef unsigned int uint_t;

// ws offsets (bytes)
// 0..81.9MB: ftr2 while roi-align alive; afterwards reused:
//   pbuf1 (28 slices f32 [256][1024] = 29.4MB) @ +0
//   W1b bf16 (25.7MB) @ +33554432
//   W2b bf16 (2MB)    @ +62914560
//   then conv ping buffer mBb (25.7MB) @ +0
#define OFF_FTR2 0ull
#define OFF_PB1  0ull
#define OFF_W1B  33554432ull
#define OFF_W2B  62914560ull
#define OFF_MB   0ull
#define OFF_FTR3 81920000ull
#define OFF_FTR4 102400000ull
#define OFF_FTR5 107520000ull
#define OFF_P7   108800000ull   // p7 bf16 [256][12544] = 6.4MB
#define OFF_H1   121645056ull   // h1 bf16 [256][1024] = 0.5MB
#define OFF_H2   122693632ull   // h2 f32 [256][1024] = 1MB
#define OFF_PB2  123742208ull   // FC2 partials f32 1MB (region 4MB)
#define OFF_WDT  127936512ull   // bf16 [4][256 o][256 i]: 0.5MB
#define OFF_MA   128985088ull   // bf16 [n][196][256]: 25.7MB
#define OFF_WT   155199488ull   // bf16 [4][9][256][256]: 4.7MB -> ends ~159.9MB

__device__ inline ushort_t f2bf(float f) {
  union { float f; uint_t u; } v; v.f = f;
  uint_t r = (v.u + 0x7fffu + ((v.u >> 16) & 1u)) >> 16;
  return (ushort_t)r;
}

// ---------------- feat transpose (B,C,H,W)->(B,H,W,C) ----------------
__global__ __launch_bounds__(256) void transpose_feat(const float* __restrict__ src,
                                                      float* __restrict__ dst,
                                                      int C, int H, int W) {
  __shared__ float tile[32][33];
  int w0 = blockIdx.x * 32, c0 = blockIdx.y * 32;
  int b = blockIdx.z / H, h = blockIdx.z % H;
  int tx = threadIdx.x & 31, ty = threadIdx.x >> 5;
#pragma unroll
  for (int i = 0; i < 32; i += 8) {
    int c = c0 + ty + i, w = w0 + tx;
    float v = 0.f;
    if (c < C && w < W) v = src[((size_t)(b * C + c) * H + h) * W + w];
    tile[ty + i][tx] = v;
  }
  __syncthreads();
#pragma unroll
  for (int i = 0; i < 32; i += 8) {
    int w = w0 + ty + i, c = c0 + tx;
    if (c < C && w < W) dst[((size_t)(b * H + h) * W + w) * C + c] = tile[tx][ty + i];
  }
}

// ---------------- f32 -> bf16 convert (8 elems/thread) ----------------
__global__ __launch_bounds__(256) void cvt_bf16(const float* __restrict__ src,
                                                ushort_t* __restrict__ dst, int n8) {
  int i = blockIdx.x * 256 + threadIdx.x;
  if (i < n8) {
    float4 a = ((const float4*)src)[i * 2];
    float4 b = ((const float4*)src)[i * 2 + 1];
    short8 r;
    r[0] = (short)f2bf(a.x); r[1] = (short)f2bf(a.y);
    r[2] = (short)f2bf(a.z); r[3] = (short)f2bf(a.w);
    r[4] = (short)f2bf(b.x); r[5] = (short)f2bf(b.y);
    r[6] = (short)f2bf(b.z); r[7] = (short)f2bf(b.w);
    ((short8*)dst)[i] = r;
  }
}

// ---------------- wd (o,i,2,2) f32 -> bf16 [tap][o][i] ----------------
__global__ __launch_bounds__(256) void wd_prep(const float* __restrict__ wd,
                                               ushort_t* __restrict__ dst) {
  int idx = blockIdx.x * 256 + threadIdx.x;
  int tap = idx >> 16;
  int rest = idx & 65535;
  int o = rest >> 8, i = rest & 255;
  dst[idx] = f2bf(wd[((size_t)o * 256 + i) * 4 + tap]);
}

// ---------------- conv weights (o,i,3,3) f32 -> [tap][o][i] bf16 ----------------
__global__ __launch_bounds__(256) void conv_wprep(const float* __restrict__ w0,
                                                  const float* __restrict__ w1,
                                                  const float* __restrict__ w2,
                                                  const float* __restrict__ w3,
                                                  ushort_t* __restrict__ dst) {
  int l = blockIdx.y;
  const float* w = (l == 0) ? w0 : (l == 1) ? w1 : (l == 2) ? w2 : w3;
  int idx = blockIdx.x * 256 + threadIdx.x;
  int tap = idx >> 16;
  int rest = idx & 65535;
  int o = rest >> 8, i = rest & 255;
  dst[(size_t)l * 589824 + idx] = f2bf(w[((size_t)o * 256 + i) * 9 + tap]);
}

// ---------------- ROI align (channels-last feats), bf16 out ----------------
__global__ __launch_bounds__(256) void roi_align_k(
    const float* __restrict__ t2, const float* __restrict__ t3,
    const float* __restrict__ t4, const float* __restrict__ t5,
    const float* __restrict__ boxes, const int* __restrict__ bidx,
    ushort_t* __restrict__ outp, int OUT, int CLAST) {
  int n = blockIdx.x, pix = blockIdx.y;
  int oy = pix / OUT, ox = pix % OUT;
  int c = threadIdx.x;
  float bx1 = boxes[n * 4 + 0], by1 = boxes[n * 4 + 1];
  float bx2 = boxes[n * 4 + 2], by2 = boxes[n * 4 + 3];
  float area = (bx2 - bx1) * (by2 - by1);
  float kf = floorf(4.0f + log2f(sqrtf(area) / 224.0f + 1e-6f));
  kf = fminf(fmaxf(kf, 2.0f), 5.0f);
  int lvl = (int)kf - 2;
  float scale = 0.25f / (float)(1 << lvl);
  const float* f = (lvl == 0) ? t2 : (lvl == 1) ? t3 : (lvl == 2) ? t4 : t5;
  int H = 200 >> lvl, W = 200 >> lvl;
  int b = bidx[n];
  float x1 = bx1 * scale, y1 = by1 * scale, x2 = bx2 * scale, y2 = by2 * scale;
  float rw = fmaxf(x2 - x1, 1.0f), rh = fmaxf(y2 - y1, 1.0f);
  int P = OUT * 2;
  float acc = 0.f;
#pragma unroll
  for (int sy = 0; sy < 2; ++sy) {
    float offy = ((float)(oy * 2 + sy) + 0.5f) / (float)P;
    float gy = fminf(fmaxf(y1 + offy * rh, 0.f), (float)(H - 1));
    int yy0 = (int)floorf(gy);
    int yy1 = min(yy0 + 1, H - 1);
    float ly = gy - (float)yy0;
#pragma unroll
    for (int sx = 0; sx < 2; ++sx) {
      float offx = ((float)(ox * 2 + sx) + 0.5f) / (float)P;
      float gx = fminf(fmaxf(x1 + offx * rw, 0.f), (float)(W - 1));
      int xx0 = (int)floorf(gx);
      int xx1 = min(xx0 + 1, W - 1);
      float lx = gx - (float)xx0;
      size_t base = (size_t)b * H * W * 256;
      float v00 = f[base + ((size_t)yy0 * W + xx0) * 256 + c];
      float v01 = f[base + ((size_t)yy0 * W + xx1) * 256 + c];
      float v10 = f[base + ((size_t)yy1 * W + xx0) * 256 + c];
      float v11 = f[base + ((size_t)yy1 * W + xx1) * 256 + c];
      acc += v00 * (1 - ly) * (1 - lx) + v01 * (1 - ly) * lx +
             v10 * ly * (1 - lx) + v11 * ly * lx;
    }
  }
  acc *= 0.25f;
  if (CLAST)
    outp[((size_t)n * OUT * OUT + pix) * 256 + c] = f2bf(acc);
  else
    outp[((size_t)n * 256 + c) * (OUT * OUT) + pix] = f2bf(acc);
}

// ---------------- FC GEMM via MFMA: A(M,K) bf16 * B(N,K)^T bf16 -> f32 partials ----------------
// block tile 128x512, 8 waves (2 mg x 4 ng), wave = 4Mx8N frags.
// grid (M/128, N/512, S); kslice = K/S must be multiple of 32.
// P[((z*M)+row)*N + col] = partial sum over this z's K-range.
__global__ __launch_bounds__(512, 2) void fc_mfma(const ushort_t* __restrict__ A,
                                                  const ushort_t* __restrict__ B,
                                                  float* __restrict__ P,
                                                  int M, int N, int K) {
  __shared__ ushort_t sA[128 * 40];   // 10240 B
  __shared__ ushort_t sB[512 * 40];   // 40960 B
  int tid = threadIdx.x;
  int lane15 = tid & 15, hi = (tid >> 4) & 3, wid = tid >> 6;
  int mg = wid >> 2, ng = wid & 3;
  int S = gridDim.z;
  int kslice = K / S;
  int nsteps = kslice >> 5;
  int k0 = blockIdx.z * kslice;
  const ushort_t* Ab = A + (size_t)(blockIdx.x * 128) * K + k0;
  const ushort_t* Bb = B + (size_t)(blockIdx.y * 512) * K + k0;
  int ar = tid >> 2, ap = tid & 3;   // A: 512 chunks of 16B
  int br = tid >> 2, bp = tid & 3;   // B: 2048 chunks, 4/thread

  short8 pa = *(const short8*)(Ab + (size_t)ar * K + ap * 8);
  short8 pb[4];
#pragma unroll
  for (int j = 0; j < 4; ++j)
    pb[j] = *(const short8*)(Bb + (size_t)(j * 128 + br) * K + bp * 8);
  *(short8*)&sA[ar * 40 + ap * 8] = pa;
#pragma unroll
  for (int j = 0; j < 4; ++j) *(short8*)&sB[(j * 128 + br) * 40 + bp * 8] = pb[j];

  f32x4 acc[4][8];
#pragma unroll
  for (int m = 0; m < 4; ++m)
#pragma unroll
    for (int bt = 0; bt < 8; ++bt) acc[m][bt] = (f32x4)0.f;

  for (int s = 0; s < nsteps; ++s) {
    __syncthreads();   // staged slice s visible
    if (s < nsteps - 1) {
      const ushort_t* An = Ab + (s + 1) * 32;
      const ushort_t* Bn = Bb + (s + 1) * 32;
      pa = *(const short8*)(An + (size_t)ar * K + ap * 8);
#pragma unroll
      for (int j = 0; j < 4; ++j)
        pb[j] = *(const short8*)(Bn + (size_t)(j * 128 + br) * K + bp * 8);
    }
    short8 bfr[8];
#pragma unroll
    for (int bt = 0; bt < 8; ++bt)
      bfr[bt] = *(const short8*)&sB[(ng * 128 + bt * 16 + lane15) * 40 + hi * 8];
    short8 afr[4];
#pragma unroll
    for (int m = 0; m < 4; ++m)
      afr[m] = *(const short8*)&sA[(mg * 64 + m * 16 + lane15) * 40 + hi * 8];
#pragma unroll
    for (int m = 0; m < 4; ++m)
#pragma unroll
      for (int bt = 0; bt < 8; ++bt)
        acc[m][bt] = __builtin_amdgcn_mfma_f32_16x16x32_bf16(afr[m], bfr[bt], acc[m][bt], 0, 0, 0);
    __syncthreads();   // reads done
    if (s < nsteps - 1) {
      *(short8*)&sA[ar * 40 + ap * 8] = pa;
#pragma unroll
      for (int j = 0; j < 4; ++j) *(short8*)&sB[(j * 128 + br) * 40 + bp * 8] = pb[j];
    }
  }
  size_t base = ((size_t)blockIdx.z * M + blockIdx.x * 128) * N + blockIdx.y * 512;
#pragma unroll
  for (int m = 0; m < 4; ++m)
#pragma unroll
    for (int bt = 0; bt < 8; ++bt) {
      int col = ng * 128 + bt * 16 + lane15;
#pragma unroll
      for (int r = 0; r < 4; ++r) {
        int row = mg * 64 + m * 16 + hi * 4 + r;
        P[base + (size_t)row * N + col] = acc[m][bt][r];
      }
    }
}

// ---------------- split-K reduce + bias + relu; out f32 or bf16 ----------------
__global__ __launch_bounds__(256) void reduce_bias_relu(const float* __restrict__ pb,
                                                        const float* __restrict__ bias,
                                                        void* __restrict__ out,
                                                        int MN, int N, int S, int obf) {
  int idx = blockIdx.x * 256 + threadIdx.x;
  if (idx >= MN) return;
  float v = 0.f;
  for (int s = 0; s < S; ++s) v += pb[(size_t)s * MN + idx];
  v += bias[idx % N];
  v = fmaxf(v, 0.f);
  if (obf) ((ushort_t*)out)[idx] = f2bf(v);
  else ((float*)out)[idx] = v;
}

// ---------------- cls/bbox head ----------------
__global__ __launch_bounds__(256) void head_kernel(const float* __restrict__ h2,
                                                   const float* __restrict__ Wc,
                                                   const float* __restrict__ bc,
                                                   const float* __restrict__ Wb,
                                                   const float* __restrict__ bb,
                                                   float* __restrict__ out) {
  int n = blockIdx.x;
  int tid = threadIdx.x;
  __shared__ float s[1024];
  __shared__ float red[10][4];
#pragma unroll
  for (int r = 0; r < 4; ++r) s[tid + 256 * r] = h2[(size_t)n * 1024 + tid + 256 * r];
  __syncthreads();
  for (int j = 0; j < 10; ++j) {
    const float* w = (j < 2) ? &Wc[j * 1024] : &Wb[(j - 2) * 1024];
    float v = 0.f;
#pragma unroll
    for (int r = 0; r < 4; ++r) v += s[tid + 256 * r] * w[tid + 256 * r];
#pragma unroll
    for (int off = 32; off > 0; off >>= 1) v += __shfl_down(v, off);
    if ((tid & 63) == 0) red[j][tid >> 6] = v;
  }
  __syncthreads();
  if (tid < 10) {
    float v = red[tid][0] + red[tid][1] + red[tid][2] + red[tid][3];
    if (tid < 2) out[n * 2 + tid] = v + bc[tid];
    else out[512 + n * 8 + (tid - 2)] = v + bb[tid - 2];
  }
}

// ---------------- conv3x3 via MFMA, bf16, one roi per block ----------------
__global__ __launch_bounds__(512, 2) void conv3x3_mfma(
    const ushort_t* __restrict__ in, const ushort_t* __restrict__ wT,
    const float* __restrict__ bias, ushort_t* __restrict__ out) {
  __shared__ ushort_t simg[256 * 264];   // 135168 B
  __shared__ ushort_t swt[256 * 40];     // 20480 B
  int n = blockIdx.x;
  int tid = threadIdx.x;
  int lane15 = tid & 15;
  int hi = (tid >> 4) & 3;
  int wid = tid >> 6;
  int mg = wid >> 1, ng = wid & 1;
  int mstart = (mg == 0) ? 0 : (1 + 3 * mg);
  int mcount = (mg == 0) ? 4 : 3;
  int ngbase = ng * 128;

  for (int i = tid; i < 256 * 264 / 2; i += 512) ((uint_t*)simg)[i] = 0u;
  __syncthreads();
  for (int it = 0; it < 13; ++it) {
    int idx = it * 512 + tid;
    if (idx < 6272) {
      int px = idx >> 5, part = idx & 31;
      int y = px / 14, x = px - y * 14;
      int r = (y + 1) * 16 + (x + 1);
      *(short8*)&simg[r * 264 + part * 8] =
          *(const short8*)(in + ((size_t)n * 196 + px) * 256 + part * 8);
    }
  }
  int r0[4];
#pragma unroll
  for (int m = 0; m < 4; ++m) {
    int p = (mstart + m) * 16 + lane15;
    int y = p / 14, x = p - y * 14;
    r0[m] = (p < 196) ? (y + 1) * 16 + (x + 1) : 17;
  }
  int g1 = tid, g2 = tid + 512;
  int n1 = g1 >> 2, s1 = g1 & 3;
  int n2 = g2 >> 2, s2 = g2 & 3;

  short8 pf0 = *(const short8*)(wT + (size_t)n1 * 256 + s1 * 8);
  short8 pf1 = *(const short8*)(wT + (size_t)n2 * 256 + s2 * 8);
  *(short8*)&swt[n1 * 40 + s1 * 8] = pf0;
  *(short8*)&swt[n2 * 40 + s2 * 8] = pf1;

  f32x4 acc[4][8];
#pragma unroll
  for (int m = 0; m < 4; ++m)
#pragma unroll
    for (int bt = 0; bt < 8; ++bt) acc[m][bt] = (f32x4)0.f;

  for (int it = 0; it < 72; ++it) {
    __syncthreads();
    int tap = it >> 3, ks = it & 7;
    if (it < 71) {
      int nt = it + 1;
      int ntap = nt >> 3, nks = nt & 7;
      size_t sb = (size_t)ntap * 65536 + (size_t)nks * 32;
      pf0 = *(const short8*)(wT + sb + (size_t)n1 * 256 + s1 * 8);
      pf1 = *(const short8*)(wT + sb + (size_t)n2 * 256 + s2 * 8);
    }
    int dtap = ((tap / 3) - 1) * 16 + (tap % 3) - 1;
    short8 bfr[8];
#pragma unroll
    for (int bt = 0; bt < 8; ++bt)
      bfr[bt] = *(const short8*)&swt[(ngbase + bt * 16 + lane15) * 40 + hi * 8];
#pragma unroll
    for (int m = 0; m < 4; ++m) {
      if (m < mcount) {
        short8 af = *(const short8*)&simg[(r0[m] + dtap) * 264 + ks * 32 + hi * 8];
#pragma unroll
        for (int bt = 0; bt < 8; ++bt)
          acc[m][bt] = __builtin_amdgcn_mfma_f32_16x16x32_bf16(af, bfr[bt], acc[m][bt], 0, 0, 0);
      }
    }
    __syncthreads();
    if (it < 71) {
      *(short8*)&swt[n1 * 40 + s1 * 8] = pf0;
      *(short8*)&swt[n2 * 40 + s2 * 8] = pf1;
    }
  }
#pragma unroll
  for (int m = 0; m < 4; ++m) {
    if (m < mcount) {
      int pbase = (mstart + m) * 16 + hi * 4;
#pragma unroll
      for (int bt = 0; bt < 8; ++bt) {
        int c = ngbase + bt * 16 + lane15;
        float bv = bias[c];
#pragma unroll
        for (int r = 0; r < 4; ++r) {
          int p = pbase + r;
          if (p < 196) {
            float v = fmaxf(acc[m][bt][r] + bv, 0.f);
            out[((size_t)n * 196 + p) * 256 + c] = f2bf(v);
          }
        }
      }
    }
  }
}

// ---------------- deconv 2x2 s2 + bias + relu + 1x1 conv, fused, MFMA ----------------
__global__ __launch_bounds__(512, 2) void deconv_mask_mfma(
    const ushort_t* __restrict__ in, const ushort_t* __restrict__ wdT,
    const float* __restrict__ bd, const float* __restrict__ wm5,
    const float* __restrict__ bm5, float* __restrict__ outp) {
  __shared__ ushort_t simg[208 * 264];
  __shared__ ushort_t swt[256 * 40];
  __shared__ float s_red[784];
  int n = blockIdx.x;
  int tid = threadIdx.x;
  int lane15 = tid & 15;
  int hi = (tid >> 4) & 3;
  int wid = tid >> 6;
  int mg = wid >> 1, ng = wid & 1;
  int mstart = (mg == 0) ? 0 : (1 + 3 * mg);
  int mcount = (mg == 0) ? 4 : 3;
  int ngbase = ng * 128;

  for (int it = 0; it < 13; ++it) {
    int idx = it * 512 + tid;
    if (idx < 6272) {
      int px = idx >> 5, part = idx & 31;
      *(short8*)&simg[px * 264 + part * 8] =
          *(const short8*)(in + ((size_t)n * 196 + px) * 256 + part * 8);
    }
  }
  for (int i = tid; i < 12 * 264 / 2; i += 512) ((uint_t*)&simg[196 * 264])[i] = 0u;

  float bdv[8], w0v[8], w1v[8];
#pragma unroll
  for (int bt = 0; bt < 8; ++bt) {
    int c = ngbase + bt * 16 + lane15;
    bdv[bt] = bd[c];
    w0v[bt] = wm5[c];
    w1v[bt] = wm5[256 + c];
  }
  int rowb[4];
#pragma unroll
  for (int m = 0; m < 4; ++m) rowb[m] = ((mstart + m) * 16 + lane15) * 264;

  int g1 = tid, g2 = tid + 512;
  int n1 = g1 >> 2, s1 = g1 & 3;
  int n2 = g2 >> 2, s2 = g2 & 3;

  short8 pf0 = *(const short8*)(wdT + (size_t)n1 * 256 + s1 * 8);
  short8 pf1 = *(const short8*)(wdT + (size_t)n2 * 256 + s2 * 8);
  *(short8*)&swt[n1 * 40 + s1 * 8] = pf0;
  *(short8*)&swt[n2 * 40 + s2 * 8] = pf1;

  f32x4 acc[4][8];
#pragma unroll
  for (int m = 0; m < 4; ++m)
#pragma unroll
    for (int bt = 0; bt < 8; ++bt) acc[m][bt] = (f32x4)0.f;

  for (int g = 0; g < 32; ++g) {
    __syncthreads();
    int tap = g >> 3, ks = g & 7;
    if (g < 31) {
      int ng_ = g + 1;
      size_t sb = (size_t)(ng_ >> 3) * 65536 + (size_t)(ng_ & 7) * 32;
      pf0 = *(const short8*)(wdT + sb + (size_t)n1 * 256 + s1 * 8);
      pf1 = *(const short8*)(wdT + sb + (size_t)n2 * 256 + s2 * 8);
    }
    short8 bfr[8];
#pragma unroll
    for (int bt = 0; bt < 8; ++bt)
      bfr[bt] = *(const short8*)&swt[(ngbase + bt * 16 + lane15) * 40 + hi * 8];
#pragma unroll
    for (int m = 0; m < 4; ++m) {
      if (m < mcount) {
        short8 af = *(const short8*)&simg[rowb[m] + ks * 32 + hi * 8];
#pragma unroll
        for (int bt = 0; bt < 8; ++bt)
          acc[m][bt] = __builtin_amdgcn_mfma_f32_16x16x32_bf16(af, bfr[bt], acc[m][bt], 0, 0, 0);
      }
    }
    __syncthreads();
    if (g < 31) {
      *(short8*)&swt[n1 * 40 + s1 * 8] = pf0;
      *(short8*)&swt[n2 * 40 + s2 * 8] = pf1;
    }
    if ((g & 7) == 7) {
#pragma unroll
      for (int m = 0; m < 4; ++m) {
        if (m < mcount) {
#pragma unroll
          for (int r = 0; r < 4; ++r) {
            int p = (mstart + m) * 16 + hi * 4 + r;
            float v0 = 0.f, v1 = 0.f;
#pragma unroll
            for (int bt = 0; bt < 8; ++bt) {
              float t = fmaxf(acc[m][bt][r] + bdv[bt], 0.f);
              v0 += t * w0v[bt];
              v1 += t * w1v[bt];
            }
#pragma unroll
            for (int off = 1; off < 16; off <<= 1) {
              v0 += __shfl_xor(v0, off);
              v1 += __shfl_xor(v1, off);
            }
            if (lane15 == 0 && p < 196) {
              s_red[(p * 2 + 0) * 2 + ng] = v0;
              s_red[(p * 2 + 1) * 2 + ng] = v1;
            }
          }
        }
      }
      __syncthreads();
      if (tid < 392) {
        int p = tid >> 1, k = tid & 1;
        float v = s_red[(p * 2 + k) * 2 + 0] + s_red[(p * 2 + k) * 2 + 1] + bm5[k];
        int iy = p / 14, ix = p - iy * 14;
        int ky = tap >> 1, kx = tap & 1;
        int y = 2 * iy + 1 - ky, x = 2 * ix + 1 - kx;
        outp[2560 + (size_t)n * 1568 + k * 784 + y * 28 + x] = v;
      }
#pragma unroll
      for (int m = 0; m < 4; ++m)
#pragma unroll
        for (int bt = 0; bt < 8; ++bt) acc[m][bt] = (f32x4)0.f;
    }
  }
}

// ---------------- launch ----------------
extern "C" void kernel_launch(void* const* d_in, const int* in_sizes, int n_in,
                              void* d_out, int out_size, void* d_ws, size_t ws_size,
                              hipStream_t stream) {
  const float* f2 = (const float*)d_in[0];
  const float* f3 = (const float*)d_in[1];
  const float* f4 = (const float*)d_in[2];
  const float* f5 = (const float*)d_in[3];
  const float* boxes = (const float*)d_in[4];
  const int* bidx = (const int*)d_in[5];
  const float* W1 = (const float*)d_in[6];
  const float* b1 = (const float*)d_in[7];
  const float* W2 = (const float*)d_in[8];
  const float* b2 = (const float*)d_in[9];
  const float* Wc = (const float*)d_in[10];
  const float* bc = (const float*)d_in[11];
  const float* Wb = (const float*)d_in[12];
  const float* bb = (const float*)d_in[13];
  const float* wd = (const float*)d_in[14];
  const float* bd = (const float*)d_in[15];
  const float* wm5 = (const float*)d_in[16];
  const float* bm5 = (const float*)d_in[17];
  const float* wm[4] = {(const float*)d_in[18], (const float*)d_in[20],
                        (const float*)d_in[22], (const float*)d_in[24]};
  const float* bm[4] = {(const float*)d_in[19], (const float*)d_in[21],
                        (const float*)d_in[23], (const float*)d_in[25]};
  char* ws = (char*)d_ws;
  float* ftr2 = (float*)(ws + OFF_FTR2);
  float* ftr3 = (float*)(ws + OFF_FTR3);
  float* ftr4 = (float*)(ws + OFF_FTR4);
  float* ftr5 = (float*)(ws + OFF_FTR5);
  ushort_t* p7b = (ushort_t*)(ws + OFF_P7);
  ushort_t* h1b = (ushort_t*)(ws + OFF_H1);
  float* h2 = (float*)(ws + OFF_H2);
  float* pbuf1 = (float*)(ws + OFF_PB1);
  float* pbuf2 = (float*)(ws + OFF_PB2);
  ushort_t* W1b = (ushort_t*)(ws + OFF_W1B);
  ushort_t* W2b = (ushort_t*)(ws + OFF_W2B);
  ushort_t* wdTb = (ushort_t*)(ws + OFF_WDT);
  ushort_t* mAb = (ushort_t*)(ws + OFF_MA);
  ushort_t* mBb = (ushort_t*)(ws + OFF_MB);
  ushort_t* wTl = (ushort_t*)(ws + OFF_WT);
  float* out = (float*)d_out;

  // feats -> channels-last
  transpose_feat<<<dim3(7, 8, 400), 256, 0, stream>>>(f2, ftr2, 256, 200, 200);
  transpose_feat<<<dim3(4, 8, 200), 256, 0, stream>>>(f3, ftr3, 256, 100, 100);
  transpose_feat<<<dim3(2, 8, 100), 256, 0, stream>>>(f4, ftr4, 256, 50, 50);
  transpose_feat<<<dim3(1, 8, 50), 256, 0, stream>>>(f5, ftr5, 256, 25, 25);
  wd_prep<<<1024, 256, 0, stream>>>(wd, wdTb);
  conv_wprep<<<dim3(2304, 4), 256, 0, stream>>>(wm[0], wm[1], wm[2], wm[3], wTl);

  // ROI align (last readers of ftr2 region)
  roi_align_k<<<dim3(256, 49), 256, 0, stream>>>(ftr2, ftr3, ftr4, ftr5, boxes,
                                                 bidx, p7b, 7, 0);
  roi_align_k<<<dim3(256, 196), 256, 0, stream>>>(ftr2, ftr3, ftr4, ftr5, boxes,
                                                  bidx, mAb, 14, 1);

  // FC weights -> bf16 (into ftr2 region, now dead)
  cvt_bf16<<<6272, 256, 0, stream>>>(W1, W1b, 1605632);
  cvt_bf16<<<512, 256, 0, stream>>>(W2, W2b, 131072);

  // FC head via MFMA
  fc_mfma<<<dim3(2, 2, 28), 512, 0, stream>>>(p7b, W1b, pbuf1, 256, 1024, 12544);
  reduce_bias_relu<<<1024, 256, 0, stream>>>(pbuf1, b1, h1b, 262144, 1024, 28, 1);
  fc_mfma<<<dim3(2, 2, 1), 512, 0, stream>>>(h1b, W2b, pbuf2, 256, 1024, 1024);
  reduce_bias_relu<<<1024, 256, 0, stream>>>(pbuf2, b2, h2, 262144, 1024, 1, 0);
  head_kernel<<<256, 256, 0, stream>>>(h2, Wc, bc, Wb, bb, out);

  // mask head (bf16 MFMA convs)
  conv3x3_mfma<<<256, 512, 0, stream>>>(mAb, wTl + 0 * 589824, bm[0], mBb);
  conv3x3_mfma<<<256, 512, 0, stream>>>(mBb, wTl + 1 * 589824, bm[1], mAb);
  conv3x3_mfma<<<256, 512, 0, stream>>>(mAb, wTl + 2 * 589824, bm[2], mBb);
  conv3x3_mfma<<<256, 512, 0, stream>>>(mBb, wTl + 3 * 589824, bm[3], mAb);
  deconv_mask_mfma<<<256, 512, 0, stream>>>(mAb, wdTb, bd, wm5, bm5, out);
}